// Round 7
// baseline (4798.576 us; speedup 1.0000x reference)
//
#include <hip/hip_runtime.h>
#include <stdint.h>
#include <stddef.h>

#define B_    64
#define T_    16
#define DF_   512
#define S_    196
#define DIN_  512
#define H_    8
#define DH_   64
#define DM_   1024
#define MEM_  25
#define HN_   32
#define MR_   (B_*S_)   /* 12544 rows per tick */
#define NBLK_ 128

typedef short bf16x8 __attribute__((ext_vector_type(8)));
typedef float f32x4  __attribute__((ext_vector_type(4)));

__device__ __forceinline__ float b2f(short h){
  unsigned u = ((unsigned)(unsigned short)h) << 16;
  float f; __builtin_memcpy(&f, &u, 4); return f;
}
__device__ __forceinline__ short f2b(float f){
  unsigned u; __builtin_memcpy(&u, &f, 4);
  u = (u + 0x7fffu + ((u >> 16) & 1u)) >> 16;
  return (short)(unsigned short)u;
}
__device__ __forceinline__ float clip015(float d){
  return d < 0.f ? 0.f : (d > 15.f ? 15.f : d);
}

// ---------------------------------------------------------------------------
// Lightweight grid barrier for a co-resident NBLK_-block persistent kernel.
// cg::grid_group::sync() measured ~40us/call on MI355X (R6) -- this is the
// same semantics at ~L2-atomic cost. Monotonic counter, AGENT scope.
// Release path: all threads fence, THEN barrier, THEN tid0 releases (orders
// every thread's global writes before the signal on the 8-XCD machine).
// Bounded spin: fail-open after ~25ms instead of wedging the GPU.
// ---------------------------------------------------------------------------
__device__ __forceinline__ void gsync(unsigned* cnt, unsigned& epoch){
  __syncthreads();
  __threadfence();                 // flush this thread's writes (device scope)
  __syncthreads();                 // all fences complete before the signal
  ++epoch;
  if (threadIdx.x == 0) {
    __hip_atomic_fetch_add(cnt, 1u, __ATOMIC_RELEASE, __HIP_MEMORY_SCOPE_AGENT);
    unsigned target = epoch * (unsigned)NBLK_;
    int spin = 0;
    while (__hip_atomic_load(cnt, __ATOMIC_ACQUIRE, __HIP_MEMORY_SCOPE_AGENT) < target) {
      __builtin_amdgcn_s_sleep(2);
      if (++spin > 400000) break;  // fail-open: wrong answer beats dead node
    }
  }
  __syncthreads();
  __threadfence();                 // acquire side: invalidate stale lines
}

// ---------------------------------------------------------------------------
// bf16 MFMA GEMM, SINGLE-buffered (dbuf at 64KB LDS cut occupancy 44%->23%
// and regressed 460->605us in round 5 -- guide m132 lesson).
// C[M,N] = A[M,K]@W (+bias | +LN-fold epilogue), W passed as WT[N][K].
// 128x128 tile, BK=64, 4 waves 2x2, 16x16x32 MFMA, global_load_lds width-16,
// XOR chunk swizzle (T21).
// LNEPI: C[m][n] = iv[m]*(acc - mu[m]*gw[n]) + bw[n]  (LayerNorm folded).
// ---------------------------------------------------------------------------
template<int OUTF32, int LNEPI>
__global__ __launch_bounds__(256,2) void gemm_k(
    const short* __restrict__ A, const short* __restrict__ WT,
    void* __restrict__ Cout,
    const float* __restrict__ biasA, const float* __restrict__ biasB, int nsplit,
    const float* __restrict__ mu, const float* __restrict__ iv,
    const float* __restrict__ gw, const float* __restrict__ bw,
    int M, int N, int K, int lda, int ldc)
{
  __shared__ short lA[128*64];
  __shared__ short lB[128*64];
  const int tid = threadIdx.x;
  const int w = tid >> 6, l = tid & 63;
  const int m0 = blockIdx.x * 128, n0 = blockIdx.y * 128;
  const int wm = (w >> 1) * 64, wn = (w & 1) * 64;
  f32x4 acc[4][4];
  #pragma unroll
  for (int i=0;i<4;i++)
    #pragma unroll
    for (int j=0;j<4;j++) acc[i][j] = (f32x4){0.f,0.f,0.f,0.f};

  for (int k0 = 0; k0 < K; k0 += 64) {
    #pragma unroll
    for (int rnd = 0; rnd < 4; ++rnd) {
      int cb = (rnd*4 + w) * 64;
      int slot = cb + l;
      int row = slot >> 3, kb = slot & 7;
      int kc = k0 + ((kb ^ (row & 7)) << 3);
      int gm = m0 + row; if (gm > M-1) gm = M-1;
      __builtin_amdgcn_global_load_lds(
          (const __attribute__((address_space(1))) void*)(A + (size_t)gm * lda + kc),
          (__attribute__((address_space(3))) void*)&lA[cb*8], 16, 0, 0);
      __builtin_amdgcn_global_load_lds(
          (const __attribute__((address_space(1))) void*)(WT + (size_t)(n0 + row) * K + kc),
          (__attribute__((address_space(3))) void*)&lB[cb*8], 16, 0, 0);
    }
    asm volatile("s_waitcnt vmcnt(0)" ::: "memory");
    __syncthreads();
    #pragma unroll
    for (int ks = 0; ks < 2; ++ks) {
      bf16x8 af[4], bfr[4];
      #pragma unroll
      for (int i = 0; i < 4; ++i) {
        int ra = wm + i*16 + (l & 15);
        int c  = ks*4 + (l >> 4);
        af[i]  = *(const bf16x8*)&lA[ra*64 + ((c ^ (ra & 7)) << 3)];
        int rb = wn + i*16 + (l & 15);
        bfr[i] = *(const bf16x8*)&lB[rb*64 + ((c ^ (rb & 7)) << 3)];
      }
      #pragma unroll
      for (int i = 0; i < 4; ++i)
        #pragma unroll
        for (int j = 0; j < 4; ++j)
          acc[i][j] = __builtin_amdgcn_mfma_f32_16x16x32_bf16(af[i], bfr[j], acc[i][j], 0, 0, 0);
    }
    __syncthreads();
  }
  #pragma unroll
  for (int i = 0; i < 4; ++i) {
    #pragma unroll
    for (int j = 0; j < 4; ++j) {
      int gn = n0 + wn + j*16 + (l & 15);
      float gwn = 0.f, bwn = 0.f, bb = 0.f;
      if (LNEPI) { gwn = gw[gn]; bwn = bw[gn]; }
      else bb = biasA ? ((gn < nsplit) ? biasA[gn] : biasB[gn - nsplit]) : 0.f;
      #pragma unroll
      for (int r = 0; r < 4; ++r) {
        int gm = m0 + wm + i*16 + (l >> 4)*4 + r;
        if (gm < M) {
          float v;
          if (LNEPI) v = iv[gm]*(acc[i][j][r] - mu[gm]*gwn) + bwn;
          else       v = acc[i][j][r] + bb;
          if (OUTF32) ((float*)Cout)[(size_t)gm * ldc + gn] = v;
          else        ((short*)Cout)[(size_t)gm * ldc + gn] = f2b(v);
        }
      }
    }
  }
}

// ---------------------------------------------------------------------------
// Batched transpose of x over a tick chunk: f32 [B][T][DF][S] -> bf16 rows
// ((ti*B+b)*S + s) x [DF].
// ---------------------------------------------------------------------------
__global__ __launch_bounds__(256) void xpose_x(const float* __restrict__ x,
                                               short* __restrict__ xT, int t0, int tc)
{
  __shared__ float tile[32][33];
  int df0 = blockIdx.x*32, s0 = blockIdx.y*32;
  int z = blockIdx.z;
  int b = z / tc, ti = z % tc;
  int tx = threadIdx.x & 31, ty = threadIdx.x >> 5;
  const float* src = x + (size_t)(b*T_ + t0 + ti) * DF_ * S_;
  #pragma unroll
  for (int i = 0; i < 4; ++i) {
    int df = df0 + ty + i*8;
    int s  = s0 + tx;
    tile[ty+i*8][tx] = (s < S_) ? src[(size_t)df*S_ + s] : 0.f;
  }
  __syncthreads();
  short* dst = xT + (size_t)(ti*B_ + b) * S_ * DIN_;
  #pragma unroll
  for (int i = 0; i < 4; ++i) {
    int s  = s0 + ty + i*8;
    int df = df0 + tx;
    if (s < S_) dst[(size_t)s*DF_ + df] = f2b(tile[tx][ty+i*8]);
  }
}

// Weight transpose f32->bf16, optional per-row scale:
// out[c*ldo + coff + r] = in[r][c] * (scale ? scale[r] : 1)
__global__ __launch_bounds__(256) void wtrans(const float* __restrict__ in,
    short* __restrict__ out, int R, int C, int ldo, int coff,
    const float* __restrict__ scale)
{
  __shared__ float tile[32][33];
  int c0 = blockIdx.x*32, r0 = blockIdx.y*32;
  int tx = threadIdx.x & 31, ty = threadIdx.x >> 5;
  #pragma unroll
  for (int i = 0; i < 4; ++i) {
    int r = r0+ty+i*8;
    float sc = scale ? scale[r] : 1.f;
    tile[ty+i*8][tx] = in[(size_t)r*C + c0+tx] * sc;
  }
  __syncthreads();
  #pragma unroll
  for (int i = 0; i < 4; ++i)
    out[(size_t)(c0+ty+i*8)*ldo + coff + r0+tx] = f2b(tile[tx][ty+i*8]);
}

// f32 -> bf16 flat copy
__global__ __launch_bounds__(256) void cvtb(const float* __restrict__ in,
                                            short* __restrict__ out, int n)
{
  int i = blockIdx.x*256 + threadIdx.x;
  if (i < n) out[i] = f2b(in[i]);
}

// out[n] = (base?base[n]:0) + sum_k vec[k]*W[k*ldw+n]
__global__ __launch_bounds__(256) void bias_fold(const float* __restrict__ vec,
    const float* __restrict__ W, const float* __restrict__ base,
    float* __restrict__ out, int N, int ldw)
{
  int n = blockIdx.x*256 + threadIdx.x;
  if (n >= N) return;
  float a = base ? base[n] : 0.f;
  #pragma unroll 8
  for (int k = 0; k < 512; ++k) a += vec[k]*W[(size_t)k*ldw + n];
  out[n] = a;
}

// Row permutation of WsynF so GLU pairs land in the same MFMA fragment.
__global__ __launch_bounds__(256) void permrows(const short* __restrict__ in,
                                                short* __restrict__ out)
{
  int r = blockIdx.x;
  int k = r >> 4, i = r & 15;
  int src = (i < 8) ? (k*8 + i) : (1024 + k*8 + (i - 8));
  const bf16x8* s = (const bf16x8*)(in + (size_t)src*1536);
  bf16x8* d = (bf16x8*)(out + (size_t)r*1536);
  int j = threadIdx.x;
  if (j < 192) d[j] = s[j];
}

// Per-row LayerNorm stats over 512 bf16 cols: mu[r], iv[r]. One wave per row.
__global__ __launch_bounds__(256) void ln_stats(const short* __restrict__ in,
    float* __restrict__ mu, float* __restrict__ iv, int nrows)
{
  int w = threadIdx.x >> 6, l = threadIdx.x & 63;
  int r = blockIdx.x*4 + w;
  if (r >= nrows) return;
  bf16x8 v8 = *(const bf16x8*)&in[(size_t)r*512 + l*8];
  float s = 0.f, s2 = 0.f;
  #pragma unroll
  for (int j = 0; j < 8; ++j) { float v = b2f(v8[j]); s += v; s2 += v*v; }
  #pragma unroll
  for (int m = 1; m < 64; m <<= 1) { s += __shfl_xor(s, m, 64); s2 += __shfl_xor(s2, m, 64); }
  if (l == 0) {
    float mean = s * (1.f/512.f);
    float var  = s2 * (1.f/512.f) - mean*mean;
    mu[r] = mean;
    iv[r] = rsqrtf(var + 1e-5f);
  }
}

// ---------------------------------------------------------------------------
// outk body: 512 threads, one b. out-sync, pred, entropy for tick tt.
// ---------------------------------------------------------------------------
__device__ __forceinline__ void outk_body(int tt, int b, int tid,
    float* syncL, float* wred,
    const float* actT, float* ao, float* bo_s,
    const int* li_o, const int* ri_o, const float* decay_o,
    const float* Wout, const float* bout, float* out)
{
  int j = tid;
  float rr = expf(-clip015(decay_o[j]));
  float prod = actT[li_o[j]*64 + b] * actT[ri_o[j]*64 + b];
  float a2 = rr*ao[b*512+j] + prod; ao[b*512+j] = a2;
  float bb2 = rr*bo_s[b*512+j] + 1.f; bo_s[b*512+j] = bb2;
  syncL[j] = a2 * rsqrtf(bb2);
  __syncthreads();
  float a = bout[j];
  #pragma unroll 8
  for (int k = 0; k < 512; ++k) a += syncL[k]*Wout[k*512+j];
  out[((size_t)b*512 + j)*16 + tt] = a;
  int w = tid >> 6, l = tid & 63;
  float m = a;
  #pragma unroll
  for (int k = 32; k >= 1; k >>= 1) m = fmaxf(m, __shfl_xor(m, k, 64));
  if (l == 0) wred[w] = m;
  __syncthreads();
  float M = wred[0];
  #pragma unroll
  for (int k = 1; k < 8; ++k) M = fmaxf(M, wred[k]);
  float e = expf(a - M);
  float z = e, s1 = e*(a - M);
  #pragma unroll
  for (int k = 32; k >= 1; k >>= 1) { z += __shfl_xor(z, k, 64); s1 += __shfl_xor(s1, k, 64); }
  if (l == 0) { wred[8+w] = z; wred[16+w] = s1; }
  __syncthreads();
  if (tid == 0) {
    float Z = 0.f, S1 = 0.f;
    #pragma unroll
    for (int k = 0; k < 8; ++k) { Z += wred[8+k]; S1 += wred[16+k]; }
    float plp = S1 / Z - logf(Z);
    float ne = -plp * (1.f/logf(512.f));
    out[524288 + (size_t)b*32 + tt]      = ne;
    out[524288 + (size_t)b*32 + 16 + tt] = 1.f - ne;
  }
}

// ---------------------------------------------------------------------------
// fused_ticks (persistent, custom barrier): all ticks of a chunk, one launch.
// 128 blocks x 512 threads. Per tick:
//   phase1: blocks 0-63 attn(t), blocks 64-127 outk(t-1)   -> gsync
//   phase2: synapse GEMM + GLU -> u                        -> gsync
//   phase3: LN(1024) -> hist slot + NLM -> actT, preb      -> gsync
// Final outk(T-1) after the loop when `last`.
// ---------------------------------------------------------------------------
__global__ __launch_bounds__(512) void fused_ticks(
    const short* __restrict__ KV, short* __restrict__ preb,
    const short* __restrict__ WsynP, const float* __restrict__ bsynF,
    float* __restrict__ u,
    const float* __restrict__ gsyn, const float* __restrict__ bln,
    float* __restrict__ hist,
    const float* __restrict__ W1, const float* __restrict__ b1,
    const float* __restrict__ W2, const float* __restrict__ b2,
    float* __restrict__ actT,
    const float* __restrict__ Wqq, const float* __restrict__ bqh,
    float* __restrict__ aa, float* __restrict__ ba,
    const int* __restrict__ li_a, const int* __restrict__ ri_a,
    const float* __restrict__ decay_a,
    float* __restrict__ ao, float* __restrict__ bo_s,
    const int* __restrict__ li_o, const int* __restrict__ ri_o,
    const float* __restrict__ decay_o,
    const float* __restrict__ Wout, const float* __restrict__ bout,
    float* __restrict__ out,
    unsigned* __restrict__ cnt, int t0, int tcc, int last)
{
  __shared__ __attribute__((aligned(16))) float smem[3072];
  const int bid = blockIdx.x, tid = threadIdx.x;
  unsigned epoch = 0;

  for (int ti = 0; ti < tcc; ++ti) {
    const int t = t0 + ti;
    // ---- phase 1: attn(t) || outk(t-1) ----
    if (bid < 64) {
      int b = bid;
      float* syncL = smem;
      float* qhL   = smem + 512;
      float* pL    = smem + 1024;   // 8*256
      int j = tid;
      float rr = expf(-clip015(decay_a[j]));
      float prod = actT[li_a[j]*64 + b] * actT[ri_a[j]*64 + b];
      float a2 = rr*aa[b*512+j] + prod; aa[b*512+j] = a2;
      float bb2 = rr*ba[b*512+j] + 1.f;  ba[b*512+j] = bb2;
      syncL[j] = a2 * rsqrtf(bb2);
      __syncthreads();
      float qa = bqh[j];
      #pragma unroll 8
      for (int k = 0; k < 512; ++k) qa += syncL[k]*Wqq[(size_t)k*512 + j];
      qhL[j] = qa;
      __syncthreads();
      int h = tid >> 6, l = tid & 63;
      const short* base = KV + (size_t)(ti*B_ + b) * S_ * 1024;
      float sc[4];
      #pragma unroll
      for (int r4 = 0; r4 < 4; ++r4) {
        int s = r4*64 + l;
        int sL = s < S_ ? s : S_-1;
        const short* kp = base + (size_t)sL*1024 + h*64;
        float a = 0.f;
        #pragma unroll
        for (int c = 0; c < 8; ++c) {
          bf16x8 kk = *(const bf16x8*)&kp[c*8];
          #pragma unroll
          for (int jj = 0; jj < 8; ++jj) a += qhL[h*64 + c*8 + jj] * b2f(kk[jj]);
        }
        sc[r4] = (s < S_) ? a * 0.125f : -1e30f;
      }
      float mx = fmaxf(fmaxf(sc[0], sc[1]), fmaxf(sc[2], sc[3]));
      #pragma unroll
      for (int k = 32; k >= 1; k >>= 1) mx = fmaxf(mx, __shfl_xor(mx, k, 64));
      float ps = 0.f;
      #pragma unroll
      for (int r4 = 0; r4 < 4; ++r4) {
        float p = expf(sc[r4] - mx);
        ps += p;
        pL[h*256 + r4*64 + l] = p;
      }
      #pragma unroll
      for (int k = 32; k >= 1; k >>= 1) ps += __shfl_xor(ps, k, 64);
      float inv = 1.f / ps;
      __syncthreads();
      // PV: 4 independent accumulators, deep unroll -> many loads in flight
      const short* vb = base + 512 + h*64 + l;
      const float* pp = pL + h*256;
      float ac0=0.f, ac1=0.f, ac2=0.f, ac3=0.f;
      #pragma unroll 7
      for (int s4 = 0; s4 < 49; ++s4) {
        int s = s4*4;
        ac0 += pp[s]   * b2f(vb[(size_t)s*1024]);
        ac1 += pp[s+1] * b2f(vb[(size_t)(s+1)*1024]);
        ac2 += pp[s+2] * b2f(vb[(size_t)(s+2)*1024]);
        ac3 += pp[s+3] * b2f(vb[(size_t)(s+3)*1024]);
      }
      float accv = (ac0+ac1)+(ac2+ac3);
      preb[(size_t)b*1536 + h*64 + l] = f2b(accv * inv);
    } else if (t > 0) {
      outk_body(t-1, bid-64, tid, smem, smem+512, actT, ao, bo_s,
                li_o, ri_o, decay_o, Wout, bout, out);
    }
    gsync(cnt, epoch);
    // ---- phase 2: synapse GEMM + GLU -> u ----
    {
      int w = tid >> 6, l = tid & 63;
      int mf = w & 3, kh = w >> 2;
      int arow = mf*16 + (l & 15);
      int kbase = kh*768 + (l >> 4)*8;
      const short* ap = preb + (size_t)arow*1536 + kbase;
      const short* bp = WsynP + (size_t)(bid*16 + (l & 15))*1536 + kbase;
      f32x4 acc = (f32x4){0.f,0.f,0.f,0.f};
      #pragma unroll 4
      for (int ks = 0; ks < 24; ++ks) {
        bf16x8 av = *(const bf16x8*)(ap + ks*32);
        bf16x8 bv = *(const bf16x8*)(bp + ks*32);
        acc = __builtin_amdgcn_mfma_f32_16x16x32_bf16(av, bv, acc, 0, 0, 0);
      }
      f32x4* part = (f32x4*)smem;
      part[w*64 + l] = acc;
      __syncthreads();
      if (w < 4) {
        f32x4 o1 = part[w*64 + l], o2 = part[(w+4)*64 + l];
        int c = l & 15;
        int colg = bid*8 + (c & 7);
        float bias = (c < 8) ? bsynF[colg] : bsynF[1024 + colg];
        float tv[4], pv[4];
        #pragma unroll
        for (int r2 = 0; r2 < 4; ++r2) tv[r2] = o1[r2] + o2[r2] + bias;
        #pragma unroll
        for (int r2 = 0; r2 < 4; ++r2) pv[r2] = __shfl_xor(tv[r2], 8, 64);
        if (c < 8) {
          #pragma unroll
          for (int r2 = 0; r2 < 4; ++r2) {
            float uu = tv[r2] * (1.f/(1.f + expf(-pv[r2])));
            int brow = w*16 + (l >> 4)*4 + r2;
            u[brow*1024 + colg] = uu;
          }
        }
      }
    }
    gsync(cnt, epoch);
    // ---- phase 3: LN(1024) -> hist slot + NLM ----
    {
      float* mst = smem;
      float* ist = smem + 64;
      {
        int b = tid >> 3, p = tid & 7;
        const float* up = u + b*1024 + p*128;
        float s = 0.f, s2 = 0.f;
        #pragma unroll 8
        for (int i = 0; i < 128; ++i) { float v = up[i]; s += v; s2 += v*v; }
        #pragma unroll
        for (int k = 4; k >= 1; k >>= 1) { s += __shfl_xor(s, k, 64); s2 += __shfl_xor(s2, k, 64); }
        if (p == 0) {
          float mean = s * (1.f/1024.f);
          float var  = s2 * (1.f/1024.f) - mean*mean;
          mst[b] = mean;
          ist[b] = rsqrtf(var + 1e-5f);
        }
      }
      __syncthreads();
      int n = (bid << 3) + (tid >> 6), b = tid & 63;
      float nv = (u[b*1024 + n] - mst[b]) * ist[b] * gsyn[n] + bln[n];
      int slot = t % MEM_;
      hist[((size_t)n*MEM_ + slot)*64 + b] = nv;
      float h[32];
      #pragma unroll
      for (int j = 0; j < 32; ++j) h[j] = b1[n*32+j];
      #pragma unroll 5
      for (int m = 0; m < MEM_; ++m) {
        int phys = (t + 1 + m) % MEM_;
        float hv = (m == MEM_-1) ? nv : hist[((size_t)n*MEM_ + phys)*64 + b];
        const float* wp = &W1[((size_t)n*MEM_ + m)*32];
        #pragma unroll
        for (int j = 0; j < 32; ++j) h[j] += hv * wp[j];
      }
      float acc = b2[n];
      #pragma unroll
      for (int j = 0; j < 32; ++j) acc += fmaxf(h[j], 0.f) * W2[n*32+j];
      actT[n*64 + b] = acc;
      preb[(size_t)b*1536 + 512 + n] = f2b(acc);
    }
    gsync(cnt, epoch);
  }
  if (last && bid >= 64) {
    outk_body(t0+tcc-1, bid-64, tid, smem, smem+512, actT, ao, bo_s,
              li_o, ri_o, decay_o, Wout, bout, out);
  }
}

// Re-initialize all recurrent state + barrier counters (graph-replay safe).
__global__ __launch_bounds__(256) void initk(float* __restrict__ aa, float* __restrict__ ba,
    float* __restrict__ ao, float* __restrict__ bo_s,
    float* __restrict__ actT, float* __restrict__ hist, short* __restrict__ preb,
    const float* __restrict__ init_act, const float* __restrict__ init_hist,
    const int* __restrict__ li_o, const int* __restrict__ ri_o,
    unsigned* __restrict__ cnt)
{
  int i = blockIdx.x*256 + threadIdx.x;
  if (i < 64) cnt[i] = 0u;
  if (i < 64*512) {
    aa[i] = 0.f; ba[i] = 0.f;
    int j = i & 511;
    ao[i] = init_act[li_o[j]] * init_act[ri_o[j]];
    bo_s[i] = 1.f;
  }
  if (i < 65536) {
    int n = i >> 6, b = i & 63;
    actT[i] = init_act[n];
    preb[(size_t)b*1536 + 512 + n] = f2b(init_act[n]);
  }
  if (i < DM_*MEM_*64) {
    int nm = i >> 6;
    hist[i] = init_hist[nm];
  }
}

// ---------------------------------------------------------------------------
extern "C" void kernel_launch(void* const* d_in, const int* in_sizes, int n_in,
                              void* d_out, int out_size, void* d_ws, size_t ws_size,
                              hipStream_t stream)
{
  (void)in_sizes; (void)n_in; (void)out_size;
  const float* x       = (const float*)d_in[0];
  const float* Wqp     = (const float*)d_in[1];
  const float* bqp     = (const float*)d_in[2];
  const float* Wkv     = (const float*)d_in[3];
  const float* bkv     = (const float*)d_in[4];
  const float* g_kv    = (const float*)d_in[5];
  const float* b_kv    = (const float*)d_in[6];
  const float* Wq      = (const float*)d_in[7];
  const float* bq      = (const float*)d_in[8];
  const float* Wk      = (const float*)d_in[9];
  const float* bk      = (const float*)d_in[10];
  const float* Wv      = (const float*)d_in[11];
  const float* bv      = (const float*)d_in[12];
  const float* Wo      = (const float*)d_in[13];
  const float* bo_p    = (const float*)d_in[14];
  const float* Wsyn    = (const float*)d_in[15];
  const float* bsyn    = (const float*)d_in[16];
  const float* g_syn   = (const float*)d_in[17];
  const float* b_syn   = (const float*)d_in[18];
  const float* W1      = (const float*)d_in[19];
  const float* b1      = (const float*)d_in[20];
  const float* W2      = (const float*)d_in[21];
  const float* b2      = (const float*)d_in[22];
  const float* init_act  = (const float*)d_in[23];
  const float* init_hist = (const float*)d_in[24];
  const float* decay_a = (const float*)d_in[25];
  const float* decay_o = (const float*)d_in[26];
  const float* Wout    = (const float*)d_in[27];
  const float* bout    = (const float*)d_in[28];
  const int* li_a = (const int*)d_in[29];
  const int* ri_a = (const int*)d_in[30];
  const int* li_o = (const int*)d_in[31];
  const int* ri_o = (const int*)d_in[32];

  char* ws = (char*)d_ws;
  size_t off = 0;
  auto alloc = [&](size_t bytes) { char* p = ws + off; off += (bytes + 255) & ~(size_t)255; return p; };
  short* WkvT   = (short*)alloc(512*512*2);
  short* WkkvT  = (short*)alloc(1024*512*2);     // g-scaled rows of [Wk|Wv]^T
  short* WsynF  = (short*)alloc(2048*1536*2);
  short* WsynP  = (short*)alloc(2048*1536*2);
  short* WsynTt = (short*)alloc(2048*512*2);
  short* WqpB   = (short*)alloc(512*512*2);
  short* WqT    = (short*)alloc(512*512*2);
  short* WoB    = (short*)alloc(512*512*2);
  float* Wqq    = (float*)alloc(512*512*4);
  float* bqh    = (float*)alloc(512*4);
  float* bsynF  = (float*)alloc(2048*4);
  float* gw     = (float*)alloc(1024*4);
  float* bw     = (float*)alloc(1024*4);
  short* preb   = (short*)alloc(64*1536*2);
  float* u      = (float*)alloc(64*1024*4);
  float* aa     = (float*)alloc(64*512*4);
  float* ba     = (float*)alloc(64*512*4);
  float* ao     = (float*)alloc(64*512*4);
  float* bo_s   = (float*)alloc(64*512*4);
  float* actT   = (float*)alloc(1024*64*4);
  float* hist   = (float*)alloc((size_t)1024*25*64*4);
  float* mu     = (float*)alloc((size_t)MR_*T_*4);
  float* iv     = (float*)alloc((size_t)MR_*T_*4);
  unsigned* cnt = (unsigned*)alloc(64*4);
  size_t fixed_end = off;

  const size_t PT_XT = (size_t)MR_*512*2;
  const size_t PT_KV = (size_t)MR_*1024*2;
  const size_t per_tick = PT_XT*2 + PT_KV;   // xT + kvp + KV
  size_t avail = (ws_size > fixed_end) ? ws_size - fixed_end : 0;
  int tc = (int)(avail / per_tick);
  if (tc > T_) tc = T_;
  if (tc < 1) tc = 1;

  short* xT  = (short*)(ws + fixed_end);
  short* kvp = (short*)((char*)xT  + PT_XT*tc);
  short* KV  = (short*)((char*)kvp + PT_XT*tc);

  const int BIG = 1 << 30;
  const float* FN = nullptr;

  initk<<<6400, 256, 0, stream>>>(aa, ba, ao, bo_s, actT, hist, preb,
                                  init_act, init_hist, li_o, ri_o, cnt);
  wtrans<<<dim3(16,16), 256, 0, stream>>>(Wkv, WkvT, 512, 512, 512, 0, nullptr);
  wtrans<<<dim3(16,16), 256, 0, stream>>>(Wk,  WkkvT, 512, 512, 512, 0, g_kv);
  wtrans<<<dim3(16,16), 256, 0, stream>>>(Wv,  WkkvT + (size_t)512*512, 512, 512, 512, 0, g_kv);
  wtrans<<<dim3(64,32), 256, 0, stream>>>(Wsyn + (size_t)512*2048, WsynF, 1024, 2048, 1536, 512, nullptr);
  wtrans<<<dim3(64,16), 256, 0, stream>>>(Wsyn, WsynTt, 512, 2048, 512, 0, nullptr);
  wtrans<<<dim3(16,16), 256, 0, stream>>>(Wq,  WqT, 512, 512, 512, 0, nullptr);
  cvtb<<<1024, 256, 0, stream>>>(Wqp, WqpB, 512*512);
  cvtb<<<1024, 256, 0, stream>>>(Wo,  WoB,  512*512);
  gemm_k<1,0><<<dim3(4,4), 256, 0, stream>>>(WqpB, WqT, Wqq, nullptr, nullptr, BIG,
                                             FN, FN, FN, FN, 512, 512, 512, 512, 512);
  gemm_k<0,0><<<dim3(16,4), 256, 0, stream>>>(WsynTt, WoB, WsynF, nullptr, nullptr, BIG,
                                              FN, FN, FN, FN, 2048, 512, 512, 512, 1536);
  permrows<<<2048, 256, 0, stream>>>(WsynF, WsynP);
  bias_fold<<<2, 256, 0, stream>>>(bqp,  Wq,   bq,   bqh,   512,  512);
  bias_fold<<<8, 256, 0, stream>>>(bo_p, Wsyn, bsyn, bsynF, 2048, 2048);
  bias_fold<<<2, 256, 0, stream>>>(g_kv, Wk, nullptr, gw,       512, 512);
  bias_fold<<<2, 256, 0, stream>>>(g_kv, Wv, nullptr, gw + 512, 512, 512);
  bias_fold<<<2, 256, 0, stream>>>(b_kv, Wk, bk, bw,       512, 512);
  bias_fold<<<2, 256, 0, stream>>>(b_kv, Wv, bv, bw + 512, 512, 512);

  int chunk = 0;
  for (int t0 = 0; t0 < T_; t0 += tc, ++chunk) {
    int tcc = (t0 + tc <= T_) ? tc : (T_ - t0);
    int Mc = MR_ * tcc;
    xpose_x<<<dim3(16,7,B_*tcc), 256, 0, stream>>>(x, xT, t0, tcc);
    gemm_k<0,0><<<dim3(98*tcc,4), 256, 0, stream>>>(xT, WkvT, kvp, bkv, bkv, BIG,
                                                    FN, FN, FN, FN, Mc, 512, 512, 512, 512);
    ln_stats<<<(Mc+3)/4, 256, 0, stream>>>(kvp, mu, iv, Mc);
    gemm_k<0,1><<<dim3(98*tcc,8), 256, 0, stream>>>(kvp, WkkvT, KV, nullptr, nullptr, BIG,
                                                    mu, iv, gw, bw, Mc, 1024, 512, 512, 1024);
    int last = (t0 + tcc == T_) ? 1 : 0;
    fused_ticks<<<NBLK_, 512, 0, stream>>>(KV, preb, WsynP, bsynF, u,
        g_syn, b_syn, hist, W1, b1, W2, b2, actT, Wqq, bqh,
        aa, ba, li_a, ri_a, decay_a, ao, bo_s, li_o, ri_o, decay_o,
        Wout, bout, (float*)d_out, cnt + chunk, t0, tcc, last);
  }
}

// Round 8
// 2493.551 us; speedup vs baseline: 1.9244x; 1.9244x over previous
//
#include <hip/hip_runtime.h>
#include <stdint.h>
#include <stddef.h>

#define B_    64
#define T_    16
#define DF_   512
#define S_    196
#define DIN_  512
#define H_    8
#define DH_   64
#define DM_   1024
#define MEM_  25
#define HN_   32
#define MR_   (B_*S_)   /* 12544 rows per tick */

typedef short bf16x8 __attribute__((ext_vector_type(8)));
typedef short short4v __attribute__((ext_vector_type(4)));
typedef float f32x4  __attribute__((ext_vector_type(4)));

__device__ __forceinline__ float b2f(short h){
  unsigned u = ((unsigned)(unsigned short)h) << 16;
  float f; __builtin_memcpy(&f, &u, 4); return f;
}
__device__ __forceinline__ short f2b(float f){
  unsigned u; __builtin_memcpy(&u, &f, 4);
  u = (u + 0x7fffu + ((u >> 16) & 1u)) >> 16;
  return (short)(unsigned short)u;
}
__device__ __forceinline__ float clip015(float d){
  return d < 0.f ? 0.f : (d > 15.f ? 15.f : d);
}

// ---------------------------------------------------------------------------
// bf16 MFMA GEMM, SINGLE-buffered (dbuf regressed: occupancy 44->23%, m132).
// C[M,N] = A[M,K]@W, W passed as WT[N][K]. 128x128 tile, BK=64, 4 waves 2x2,
// 16x16x32 MFMA, global_load_lds width-16, XOR chunk swizzle (T21).
// LNEPI=0: C += bias (biasA/biasB split at nsplit).
// LNEPI=2: transposed LayerNorm fold: C[gm][gn] = iv[gn]*(acc - mu[gn]*gw[gm])
//          + bw[gm]  (column-indexed stats; used for KVT = W @ kv^T).
// ---------------------------------------------------------------------------
template<int OUTF32, int LNEPI>
__global__ __launch_bounds__(256,2) void gemm_k(
    const short* __restrict__ A, const short* __restrict__ WT,
    void* __restrict__ Cout,
    const float* __restrict__ biasA, const float* __restrict__ biasB, int nsplit,
    const float* __restrict__ mu, const float* __restrict__ iv,
    const float* __restrict__ gw, const float* __restrict__ bw,
    int M, int N, int K, int lda, int ldc)
{
  __shared__ short lA[128*64];
  __shared__ short lB[128*64];
  const int tid = threadIdx.x;
  const int w = tid >> 6, l = tid & 63;
  const int m0 = blockIdx.x * 128, n0 = blockIdx.y * 128;
  const int wm = (w >> 1) * 64, wn = (w & 1) * 64;
  f32x4 acc[4][4];
  #pragma unroll
  for (int i=0;i<4;i++)
    #pragma unroll
    for (int j=0;j<4;j++) acc[i][j] = (f32x4){0.f,0.f,0.f,0.f};

  for (int k0 = 0; k0 < K; k0 += 64) {
    #pragma unroll
    for (int rnd = 0; rnd < 4; ++rnd) {
      int cb = (rnd*4 + w) * 64;
      int slot = cb + l;
      int row = slot >> 3, kb = slot & 7;
      int kc = k0 + ((kb ^ (row & 7)) << 3);
      int gm = m0 + row; if (gm > M-1) gm = M-1;
      __builtin_amdgcn_global_load_lds(
          (const __attribute__((address_space(1))) void*)(A + (size_t)gm * lda + kc),
          (__attribute__((address_space(3))) void*)&lA[cb*8], 16, 0, 0);
      __builtin_amdgcn_global_load_lds(
          (const __attribute__((address_space(1))) void*)(WT + (size_t)(n0 + row) * K + kc),
          (__attribute__((address_space(3))) void*)&lB[cb*8], 16, 0, 0);
    }
    asm volatile("s_waitcnt vmcnt(0)" ::: "memory");
    __syncthreads();
    #pragma unroll
    for (int ks = 0; ks < 2; ++ks) {
      bf16x8 af[4], bfr[4];
      #pragma unroll
      for (int i = 0; i < 4; ++i) {
        int ra = wm + i*16 + (l & 15);
        int c  = ks*4 + (l >> 4);
        af[i]  = *(const bf16x8*)&lA[ra*64 + ((c ^ (ra & 7)) << 3)];
        int rb = wn + i*16 + (l & 15);
        bfr[i] = *(const bf16x8*)&lB[rb*64 + ((c ^ (rb & 7)) << 3)];
      }
      #pragma unroll
      for (int i = 0; i < 4; ++i)
        #pragma unroll
        for (int j = 0; j < 4; ++j)
          acc[i][j] = __builtin_amdgcn_mfma_f32_16x16x32_bf16(af[i], bfr[j], acc[i][j], 0, 0, 0);
    }
    __syncthreads();
  }
  #pragma unroll
  for (int i = 0; i < 4; ++i) {
    #pragma unroll
    for (int j = 0; j < 4; ++j) {
      int gn = n0 + wn + j*16 + (l & 15);
      float ivn = 0.f, mun = 0.f, bb = 0.f;
      if (LNEPI == 2) { ivn = iv[gn]; mun = mu[gn]; }
      else bb = biasA ? ((gn < nsplit) ? biasA[gn] : biasB[gn - nsplit]) : 0.f;
      #pragma unroll
      for (int r = 0; r < 4; ++r) {
        int gm = m0 + wm + i*16 + (l >> 4)*4 + r;
        if (gm < M) {
          float v;
          if (LNEPI == 2) v = ivn*(acc[i][j][r] - mun*gw[gm]) + bw[gm];
          else            v = acc[i][j][r] + bb;
          if (OUTF32) ((float*)Cout)[(size_t)gm * ldc + gn] = v;
          else        ((short*)Cout)[(size_t)gm * ldc + gn] = f2b(v);
        }
      }
    }
  }
}

// ---------------------------------------------------------------------------
// Batched transpose of x over a tick chunk: f32 [B][T][DF][S] -> bf16 rows
// ((ti*B+b)*S + s) x [DF].
// ---------------------------------------------------------------------------
__global__ __launch_bounds__(256) void xpose_x(const float* __restrict__ x,
                                               short* __restrict__ xT, int t0, int tc)
{
  __shared__ float tile[32][33];
  int df0 = blockIdx.x*32, s0 = blockIdx.y*32;
  int z = blockIdx.z;
  int b = z / tc, ti = z % tc;
  int tx = threadIdx.x & 31, ty = threadIdx.x >> 5;
  const float* src = x + (size_t)(b*T_ + t0 + ti) * DF_ * S_;
  #pragma unroll
  for (int i = 0; i < 4; ++i) {
    int df = df0 + ty + i*8;
    int s  = s0 + tx;
    tile[ty+i*8][tx] = (s < S_) ? src[(size_t)df*S_ + s] : 0.f;
  }
  __syncthreads();
  short* dst = xT + (size_t)(ti*B_ + b) * S_ * DIN_;
  #pragma unroll
  for (int i = 0; i < 4; ++i) {
    int s  = s0 + ty + i*8;
    int df = df0 + tx;
    if (s < S_) dst[(size_t)s*DF_ + df] = f2b(tile[tx][ty+i*8]);
  }
}

// Weight transpose f32->bf16, optional per-row scale:
// out[c*ldo + coff + r] = in[r][c] * (scale ? scale[r] : 1)
__global__ __launch_bounds__(256) void wtrans(const float* __restrict__ in,
    short* __restrict__ out, int R, int C, int ldo, int coff,
    const float* __restrict__ scale)
{
  __shared__ float tile[32][33];
  int c0 = blockIdx.x*32, r0 = blockIdx.y*32;
  int tx = threadIdx.x & 31, ty = threadIdx.x >> 5;
  #pragma unroll
  for (int i = 0; i < 4; ++i) {
    int r = r0+ty+i*8;
    float sc = scale ? scale[r] : 1.f;
    tile[ty+i*8][tx] = in[(size_t)r*C + c0+tx] * sc;
  }
  __syncthreads();
  #pragma unroll
  for (int i = 0; i < 4; ++i)
    out[(size_t)(c0+ty+i*8)*ldo + coff + r0+tx] = f2b(tile[tx][ty+i*8]);
}

// f32 -> bf16 flat copy
__global__ __launch_bounds__(256) void cvtb(const float* __restrict__ in,
                                            short* __restrict__ out, int n)
{
  int i = blockIdx.x*256 + threadIdx.x;
  if (i < n) out[i] = f2b(in[i]);
}

// out[n] = (base?base[n]:0) + sum_k vec[k]*W[k*ldw+n]
__global__ __launch_bounds__(256) void bias_fold(const float* __restrict__ vec,
    const float* __restrict__ W, const float* __restrict__ base,
    float* __restrict__ out, int N, int ldw)
{
  int n = blockIdx.x*256 + threadIdx.x;
  if (n >= N) return;
  float a = base ? base[n] : 0.f;
  #pragma unroll 8
  for (int k = 0; k < 512; ++k) a += vec[k]*W[(size_t)k*ldw + n];
  out[n] = a;
}

// Row permutation of WsynF so GLU pairs land in the same MFMA fragment.
__global__ __launch_bounds__(256) void permrows(const short* __restrict__ in,
                                                short* __restrict__ out)
{
  int r = blockIdx.x;
  int k = r >> 4, i = r & 15;
  int src = (i < 8) ? (k*8 + i) : (1024 + k*8 + (i - 8));
  const bf16x8* s = (const bf16x8*)(in + (size_t)src*1536);
  bf16x8* d = (bf16x8*)(out + (size_t)r*1536);
  int j = threadIdx.x;
  if (j < 192) d[j] = s[j];
}

// Per-row LayerNorm stats over 512 bf16 cols: mu[r], iv[r]. One wave per row.
__global__ __launch_bounds__(256) void ln_stats(const short* __restrict__ in,
    float* __restrict__ mu, float* __restrict__ iv, int nrows)
{
  int w = threadIdx.x >> 6, l = threadIdx.x & 63;
  int r = blockIdx.x*4 + w;
  if (r >= nrows) return;
  bf16x8 v8 = *(const bf16x8*)&in[(size_t)r*512 + l*8];
  float s = 0.f, s2 = 0.f;
  #pragma unroll
  for (int j = 0; j < 8; ++j) { float v = b2f(v8[j]); s += v; s2 += v*v; }
  #pragma unroll
  for (int m = 1; m < 64; m <<= 1) { s += __shfl_xor(s, m, 64); s2 += __shfl_xor(s2, m, 64); }
  if (l == 0) {
    float mean = s * (1.f/512.f);
    float var  = s2 * (1.f/512.f) - mean*mean;
    mu[r] = mean;
    iv[r] = rsqrtf(var + 1e-5f);
  }
}

// ---------------------------------------------------------------------------
// outk body: 512 threads, one b. out-sync, pred, entropy for tick tt.
// ---------------------------------------------------------------------------
__device__ __forceinline__ void outk_body(int tt, int b, int tid,
    float* syncL, float* wred,
    const float* actT, float* ao, float* bo_s,
    const int* li_o, const int* ri_o, const float* decay_o,
    const short* WoutB, const float* bout, float* out)
{
  int j = tid;
  float rr = expf(-clip015(decay_o[j]));
  float prod = actT[li_o[j]*64 + b] * actT[ri_o[j]*64 + b];
  float a2 = rr*ao[b*512+j] + prod; ao[b*512+j] = a2;
  float bb2 = rr*bo_s[b*512+j] + 1.f; bo_s[b*512+j] = bb2;
  syncL[j] = a2 * rsqrtf(bb2);
  __syncthreads();
  float a = bout[j];
  #pragma unroll 8
  for (int k = 0; k < 512; ++k) a += syncL[k]*b2f(WoutB[k*512+j]);
  out[((size_t)b*512 + j)*16 + tt] = a;
  int w = tid >> 6, l = tid & 63;
  float m = a;
  #pragma unroll
  for (int k = 32; k >= 1; k >>= 1) m = fmaxf(m, __shfl_xor(m, k, 64));
  if (l == 0) wred[w] = m;
  __syncthreads();
  float M = wred[0];
  #pragma unroll
  for (int k = 1; k < 8; ++k) M = fmaxf(M, wred[k]);
  float e = expf(a - M);
  float z = e, s1 = e*(a - M);
  #pragma unroll
  for (int k = 32; k >= 1; k >>= 1) { z += __shfl_xor(z, k, 64); s1 += __shfl_xor(s1, k, 64); }
  if (l == 0) { wred[8+w] = z; wred[16+w] = s1; }
  __syncthreads();
  if (tid == 0) {
    float Z = 0.f, S1 = 0.f;
    #pragma unroll
    for (int k = 0; k < 8; ++k) { Z += wred[8+k]; S1 += wred[16+k]; }
    float plp = S1 / Z - logf(Z);
    float ne = -plp * (1.f/logf(512.f));
    out[524288 + (size_t)b*32 + tt]      = ne;
    out[524288 + (size_t)b*32 + 16 + tt] = 1.f - ne;
  }
}

// ---------------------------------------------------------------------------
// tick_ao: blocks 0-63 = attn(t) for b=bid (KVT layout: K^T rows 0..511,
// V^T rows 512..1023, row stride ldkv); blocks 64-127 = outk(t-1).
// ---------------------------------------------------------------------------
__global__ __launch_bounds__(512) void tick_ao(
    const float* __restrict__ actT,
    float* __restrict__ aa, float* __restrict__ ba,
    const int* __restrict__ li_a, const int* __restrict__ ri_a,
    const float* __restrict__ decay_a,
    const short* __restrict__ WqqB, const float* __restrict__ bqh,
    const short* __restrict__ KVT, int ldkv, int ti,
    short* __restrict__ preb,
    float* __restrict__ ao, float* __restrict__ bo_s,
    const int* __restrict__ li_o, const int* __restrict__ ri_o,
    const float* __restrict__ decay_o,
    const short* __restrict__ WoutB, const float* __restrict__ bout,
    float* __restrict__ out, int t)
{
  __shared__ __attribute__((aligned(16))) float smem[3072];
  const int bid = blockIdx.x, tid = threadIdx.x;
  if (bid < 64) {
    int b = bid;
    float* syncL = smem;
    float* qhL   = smem + 512;
    float* pL    = smem + 1024;   // 8*256
    int j = tid;
    float rr = expf(-clip015(decay_a[j]));
    float prod = actT[li_a[j]*64 + b] * actT[ri_a[j]*64 + b];
    float a2 = rr*aa[b*512+j] + prod; aa[b*512+j] = a2;
    float bb2 = rr*ba[b*512+j] + 1.f;  ba[b*512+j] = bb2;
    syncL[j] = a2 * rsqrtf(bb2);
    __syncthreads();
    float qa = bqh[j];
    #pragma unroll 8
    for (int k = 0; k < 512; ++k) qa += syncL[k]*b2f(WqqB[k*512+j]);
    qhL[j] = qa;
    __syncthreads();
    int h = tid >> 6, l = tid & 63;
    const size_t cb = (size_t)(ti*B_ + b) * S_;
    // scores: K^T rows, lanes read contiguous s
    const short* Kb = KVT + (size_t)(h*64)*ldkv + cb;
    int s3 = 192 + l; int s3c = s3 < S_ ? s3 : S_-1;
    float sc0=0.f, sc1=0.f, sc2=0.f, sc3=0.f;
    #pragma unroll 8
    for (int d = 0; d < 64; ++d) {
      const short* kr = Kb + (size_t)d*ldkv;
      float qv = qhL[h*64 + d];
      sc0 += qv * b2f(kr[l]);
      sc1 += qv * b2f(kr[64 + l]);
      sc2 += qv * b2f(kr[128 + l]);
      sc3 += qv * b2f(kr[s3c]);
    }
    sc0 *= 0.125f; sc1 *= 0.125f; sc2 *= 0.125f;
    sc3 = (s3 < S_) ? sc3*0.125f : -1e30f;
    float mx = fmaxf(fmaxf(sc0, sc1), fmaxf(sc2, sc3));
    #pragma unroll
    for (int k = 32; k >= 1; k >>= 1) mx = fmaxf(mx, __shfl_xor(mx, k, 64));
    float p0 = expf(sc0-mx), p1 = expf(sc1-mx), p2 = expf(sc2-mx), p3 = expf(sc3-mx);
    pL[h*256 + l] = p0; pL[h*256 + 64+l] = p1;
    pL[h*256 + 128+l] = p2; pL[h*256 + 192+l] = p3;
    float ps = p0+p1+p2+p3;
    #pragma unroll
    for (int k = 32; k >= 1; k >>= 1) ps += __shfl_xor(ps, k, 64);
    float inv = 1.f / ps;
    __syncthreads();
    // PV: V^T row per thread, contiguous short4 reads
    const short4v* vrow = (const short4v*)(KVT + (size_t)(512 + h*64 + l)*ldkv + cb);
    const float* pp = pL + h*256;
    float ac0=0.f, ac1=0.f, ac2=0.f, ac3=0.f;
    #pragma unroll 7
    for (int c = 0; c < 49; ++c) {
      short4v v4 = vrow[c];
      ac0 += pp[c*4]   * b2f(v4.x);
      ac1 += pp[c*4+1] * b2f(v4.y);
      ac2 += pp[c*4+2] * b2f(v4.z);
      ac3 += pp[c*4+3] * b2f(v4.w);
    }
    float accv = (ac0+ac1)+(ac2+ac3);
    preb[(size_t)b*1536 + h*64 + l] = f2b(accv * inv);
  } else if (t > 0) {
    outk_body(t-1, bid-64, tid, smem, smem+512, actT, ao, bo_s,
              li_o, ri_o, decay_o, WoutB, bout, out);
  }
}

// Final outk for t = T-1.
__global__ __launch_bounds__(512) void outk_fin(
    const float* __restrict__ actT,
    float* __restrict__ ao, float* __restrict__ bo_s,
    const int* __restrict__ li_o, const int* __restrict__ ri_o,
    const float* __restrict__ decay_o,
    const short* __restrict__ WoutB, const float* __restrict__ bout,
    float* __restrict__ out)
{
  __shared__ __attribute__((aligned(16))) float smem[544];
  outk_body(T_-1, blockIdx.x, threadIdx.x, smem, smem+512, actT, ao, bo_s,
            li_o, ri_o, decay_o, WoutB, bout, out);
}

// ---------------------------------------------------------------------------
// syn_glu: synapse GEMM (full K=1536) + GLU -> u[64][1024].
// 128 blocks x 512 thr; block bid owns 16 permuted weight rows
// (= 8 GLU (a,gate) col pairs). 8 waves = 4 m-fragments x 2 K-halves.
// ---------------------------------------------------------------------------
__global__ __launch_bounds__(512) void syn_glu(const short* __restrict__ preb,
    const short* __restrict__ WsynP, const float* __restrict__ bsynF,
    float* __restrict__ u)
{
  __shared__ f32x4 part[512];
  const int bid = blockIdx.x, tid = threadIdx.x;
  int w = tid >> 6, l = tid & 63;
  int mf = w & 3, kh = w >> 2;
  int arow = mf*16 + (l & 15);
  int kbase = kh*768 + (l >> 4)*8;
  const short* ap = preb + (size_t)arow*1536 + kbase;
  const short* bp = WsynP + (size_t)(bid*16 + (l & 15))*1536 + kbase;
  f32x4 acc = (f32x4){0.f,0.f,0.f,0.f};
  #pragma unroll 4
  for (int ks = 0; ks < 24; ++ks) {
    bf16x8 av = *(const bf16x8*)(ap + ks*32);
    bf16x8 bv = *(const bf16x8*)(bp + ks*32);
    acc = __builtin_amdgcn_mfma_f32_16x16x32_bf16(av, bv, acc, 0, 0, 0);
  }
  part[w*64 + l] = acc;
  __syncthreads();
  if (w < 4) {
    f32x4 o1 = part[w*64 + l], o2 = part[(w+4)*64 + l];
    int c = l & 15;
    int colg = bid*8 + (c & 7);
    float bias = (c < 8) ? bsynF[colg] : bsynF[1024 + colg];
    float tv[4], pv[4];
    #pragma unroll
    for (int r2 = 0; r2 < 4; ++r2) tv[r2] = o1[r2] + o2[r2] + bias;
    #pragma unroll
    for (int r2 = 0; r2 < 4; ++r2) pv[r2] = __shfl_xor(tv[r2], 8, 64);
    if (c < 8) {
      #pragma unroll
      for (int r2 = 0; r2 < 4; ++r2) {
        float uu = tv[r2] * (1.f/(1.f + expf(-pv[r2])));
        int brow = w*16 + (l >> 4)*4 + r2;
        u[brow*1024 + colg] = uu;
      }
    }
  }
}

// ---------------------------------------------------------------------------
// nlm_ln: per-batch LN stats over u (redundant per block, L2-resident),
// write new hist slot, run NLM -> actT + preb[:,512:]. 128 blocks x 512 thr.
// ---------------------------------------------------------------------------
__global__ __launch_bounds__(512) void nlm_ln(const float* __restrict__ u,
    const float* __restrict__ gsyn, const float* __restrict__ bln,
    float* __restrict__ hist,
    const float* __restrict__ W1, const float* __restrict__ b1,
    const float* __restrict__ W2, const float* __restrict__ b2,
    float* __restrict__ actT, short* __restrict__ preb, int t)
{
  __shared__ float mstat[64], istat[64];
  const int bid = blockIdx.x, tid = threadIdx.x;
  {
    int b = tid >> 3, p = tid & 7;
    const float* up = u + b*1024 + p*128;
    float s = 0.f, s2 = 0.f;
    #pragma unroll 8
    for (int i = 0; i < 128; ++i) { float v = up[i]; s += v; s2 += v*v; }
    #pragma unroll
    for (int k = 4; k >= 1; k >>= 1) { s += __shfl_xor(s, k, 64); s2 += __shfl_xor(s2, k, 64); }
    if (p == 0) {
      float mean = s * (1.f/1024.f);
      float var  = s2 * (1.f/1024.f) - mean*mean;
      mstat[b] = mean;
      istat[b] = rsqrtf(var + 1e-5f);
    }
  }
  __syncthreads();
  int n = (bid << 3) + (tid >> 6), b = tid & 63;
  float nv = (u[b*1024 + n] - mstat[b]) * istat[b] * gsyn[n] + bln[n];
  int slot = t % MEM_;
  hist[((size_t)n*MEM_ + slot)*64 + b] = nv;
  float h[32];
  #pragma unroll
  for (int j = 0; j < 32; ++j) h[j] = b1[n*32+j];
  #pragma unroll 5
  for (int m = 0; m < MEM_; ++m) {
    int phys = (t + 1 + m) % MEM_;
    float hv = (m == MEM_-1) ? nv : hist[((size_t)n*MEM_ + phys)*64 + b];
    const float* wp = &W1[((size_t)n*MEM_ + m)*32];
    #pragma unroll
    for (int j = 0; j < 32; ++j) h[j] += hv * wp[j];
  }
  float acc = b2[n];
  #pragma unroll
  for (int j = 0; j < 32; ++j) acc += fmaxf(h[j], 0.f) * W2[n*32+j];
  actT[n*64 + b] = acc;
  preb[(size_t)b*1536 + 512 + n] = f2b(acc);
}

// Re-initialize all recurrent state (graph-replay deterministic).
__global__ __launch_bounds__(256) void initk(float* __restrict__ aa, float* __restrict__ ba,
    float* __restrict__ ao, float* __restrict__ bo_s,
    float* __restrict__ actT, float* __restrict__ hist, short* __restrict__ preb,
    const float* __restrict__ init_act, const float* __restrict__ init_hist,
    const int* __restrict__ li_o, const int* __restrict__ ri_o)
{
  int i = blockIdx.x*256 + threadIdx.x;
  if (i < 64*512) {
    aa[i] = 0.f; ba[i] = 0.f;
    int j = i & 511;
    ao[i] = init_act[li_o[j]] * init_act[ri_o[j]];
    bo_s[i] = 1.f;
  }
  if (i < 65536) {
    int n = i >> 6, b = i & 63;
    actT[i] = init_act[n];
    preb[(size_t)b*1536 + 512 + n] = f2b(init_act[n]);
  }
  if (i < DM_*MEM_*64) {
    int nm = i >> 6;
    hist[i] = init_hist[nm];
  }
}

// ---------------------------------------------------------------------------
extern "C" void kernel_launch(void* const* d_in, const int* in_sizes, int n_in,
                              void* d_out, int out_size, void* d_ws, size_t ws_size,
                              hipStream_t stream)
{
  (void)in_sizes; (void)n_in; (void)out_size;
  const float* x       = (const float*)d_in[0];
  const float* Wqp     = (const float*)d_in[1];
  const float* bqp     = (const float*)d_in[2];
  const float* Wkv     = (const float*)d_in[3];
  const float* bkv     = (const float*)d_in[4];
  const float* g_kv    = (const float*)d_in[5];
  const float* b_kv    = (const float*)d_in[6];
  const float* Wq      = (const float*)d_in[7];
  const float* bq      = (const float*)d_in[8];
  const float* Wk      = (const float*)d_in[9];
  const float* bk      = (const float*)d_in[10];
  const float* Wv      = (const float*)d_in[11];
  const float* bv      = (const float*)d_in[12];
  const float* Wo      = (const float*)d_in[13];
  const float* bo_p    = (const float*)d_in[14];
  const float* Wsyn    = (const float*)d_in[15];
  const float* bsyn    = (const float*)d_in[16];
  const float* g_syn   = (const float*)d_in[17];
  const float* b_syn   = (const float*)d_in[18];
  const float* W1      = (const float*)d_in[19];
  const float* b1      = (const float*)d_in[20];
  const float* W2      = (const float*)d_in[21];
  const float* b2      = (const float*)d_in[22];
  const float* init_act  = (const float*)d_in[23];
  const float* init_hist = (const float*)d_in[24];
  const float* decay_a = (const float*)d_in[25];
  const float* decay_o = (const float*)d_in[26];
  const float* Wout    = (const float*)d_in[27];
  const float* bout    = (const float*)d_in[28];
  const int* li_a = (const int*)d_in[29];
  const int* ri_a = (const int*)d_in[30];
  const int* li_o = (const int*)d_in[31];
  const int* ri_o = (const int*)d_in[32];

  char* ws = (char*)d_ws;
  size_t off = 0;
  auto alloc = [&](size_t bytes) { char* p = ws + off; off += (bytes + 255) & ~(size_t)255; return p; };
  short* WkvT   = (short*)alloc(512*512*2);
  short* WkkvT  = (short*)alloc(1024*512*2);     // g-scaled rows of [Wk|Wv]^T
  short* WsynF  = (short*)alloc(2048*1536*2);
  short* WsynP  = (short*)alloc(2048*1536*2);
  short* WsynTt = (short*)alloc(2048*512*2);
  short* WqpB   = (short*)alloc(512*512*2);
  short* WqT    = (short*)alloc(512*512*2);
  short* WoB    = (short*)alloc(512*512*2);
  short* WqqB   = (short*)alloc(512*512*2);
  short* WoutB  = (short*)alloc(512*512*2);
  float* bqh    = (float*)alloc(512*4);
  float* bsynF  = (float*)alloc(2048*4);
  float* gw     = (float*)alloc(1024*4);
  float* bw     = (float*)alloc(1024*4);
  short* preb   = (short*)alloc(64*1536*2);
  float* u      = (float*)alloc(64*1024*4);
  float* aa     = (float*)alloc(64*512*4);
  float* ba     = (float*)alloc(64*512*4);
  float* ao     = (float*)alloc(64*512*4);
  float* bo_s   = (float*)alloc(64*512*4);
  float* actT   = (float*)alloc(1024*64*4);
  float* hist   = (float*)alloc((size_t)1024*25*64*4);
  float* mu     = (float*)alloc((size_t)MR_*T_*4);
  float* iv     = (float*)alloc((size_t)MR_*T_*4);
  size_t fixed_end = off;

  const size_t PT_XT = (size_t)MR_*512*2;    // 12.8 MB (xT, kvp each)
  const size_t PT_KV = (size_t)MR_*1024*2;   // 25.7 MB (KVT rows per tick)
  const size_t per_tick = PT_XT*2 + PT_KV;
  size_t avail = (ws_size > fixed_end + 512) ? ws_size - fixed_end - 512 : 0;
  int tc = (int)(avail / per_tick);
  if (tc > T_) tc = T_;
  if (tc < 1) tc = 1;

  short* xT  = (short*)(ws + fixed_end);
  short* kvp = (short*)((char*)xT  + PT_XT*tc);
  short* KVT = (short*)((char*)kvp + PT_XT*tc);

  const int BIG = 1 << 30;
  const float* FN = nullptr;

  initk<<<6400, 256, 0, stream>>>(aa, ba, ao, bo_s, actT, hist, preb,
                                  init_act, init_hist, li_o, ri_o);
  wtrans<<<dim3(16,16), 256, 0, stream>>>(Wkv, WkvT, 512, 512, 512, 0, nullptr);
  wtrans<<<dim3(16,16), 256, 0, stream>>>(Wk,  WkkvT, 512, 512, 512, 0, g_kv);
  wtrans<<<dim3(16,16), 256, 0, stream>>>(Wv,  WkkvT + (size_t)512*512, 512, 512, 512, 0, g_kv);
  wtrans<<<dim3(64,32), 256, 0, stream>>>(Wsyn + (size_t)512*2048, WsynF, 1024, 2048, 1536, 512, nullptr);
  wtrans<<<dim3(64,16), 256, 0, stream>>>(Wsyn, WsynTt, 512, 2048, 512, 0, nullptr);
  wtrans<<<dim3(16,16), 256, 0, stream>>>(Wq,  WqT, 512, 512, 512, 0, nullptr);
  cvtb<<<1024, 256, 0, stream>>>(Wqp, WqpB, 512*512);
  cvtb<<<1024, 256, 0, stream>>>(Wo,  WoB,  512*512);
  cvtb<<<1024, 256, 0, stream>>>(Wout, WoutB, 512*512);
  // WqqB = Wqp @ Wq (bf16)
  gemm_k<0,0><<<dim3(4,4), 256, 0, stream>>>(WqpB, WqT, WqqB, nullptr, nullptr, BIG,
                                             FN, FN, FN, FN, 512, 512, 512, 512, 512);
  // WsynF[:, 0:512] = (Wsyn_top^T) @ (Wo^T)
  gemm_k<0,0><<<dim3(16,4), 256, 0, stream>>>(WsynTt, WoB, WsynF, nullptr, nullptr, BIG,
                                              FN, FN, FN, FN, 2048, 512, 512, 512, 1536);
  permrows<<<2048, 256, 0, stream>>>(WsynF, WsynP);
  bias_fold<<<2, 256, 0, stream>>>(bqp,  Wq,   bq,   bqh,   512,  512);
  bias_fold<<<8, 256, 0, stream>>>(bo_p, Wsyn, bsyn, bsynF, 2048, 2048);
  bias_fold<<<2, 256, 0, stream>>>(g_kv, Wk, nullptr, gw,       512, 512);
  bias_fold<<<2, 256, 0, stream>>>(g_kv, Wv, nullptr, gw + 512, 512, 512);
  bias_fold<<<2, 256, 0, stream>>>(b_kv, Wk, bk, bw,       512, 512);
  bias_fold<<<2, 256, 0, stream>>>(b_kv, Wv, bv, bw + 512, 512, 512);

  for (int t0 = 0; t0 < T_; t0 += tc) {
    int tcc = (t0 + tc <= T_) ? tc : (T_ - t0);
    int Mc = MR_ * tcc;
    xpose_x<<<dim3(16,7,B_*tcc), 256, 0, stream>>>(x, xT, t0, tcc);
    gemm_k<0,0><<<dim3(98*tcc,4), 256, 0, stream>>>(xT, WkvT, kvp, bkv, bkv, BIG,
                                                    FN, FN, FN, FN, Mc, 512, 512, 512, 512);
    ln_stats<<<Mc/4, 256, 0, stream>>>(kvp, mu, iv, Mc);
    // KVT[1024][Mc] = WkkvT @ kvp^T with transposed-LN epilogue
    gemm_k<0,2><<<dim3(8,98*tcc), 256, 0, stream>>>(WkkvT, kvp, KVT, nullptr, nullptr, BIG,
                                                    mu, iv, gw, bw, 1024, Mc, 512, 512, Mc);
    for (int ti = 0; ti < tcc; ++ti) {
      int t = t0 + ti;
      tick_ao<<<128, 512, 0, stream>>>(actT, aa, ba, li_a, ri_a, decay_a,
                                       WqqB, bqh, KVT, Mc, ti, preb,
                                       ao, bo_s, li_o, ri_o, decay_o,
                                       WoutB, bout, (float*)d_out, t);
      syn_glu<<<128, 512, 0, stream>>>(preb, WsynP, bsynF, u);
      nlm_ln<<<128, 512, 0, stream>>>(u, g_syn, b_syn, hist,
                                      W1, b1, W2, b2, actT, preb, t);
    }
  }
  outk_fin<<<64, 512, 0, stream>>>(actT, ao, bo_s, li_o, ri_o, decay_o,
                                   WoutB, bout, (float*)d_out);
}

// Round 10
// 2442.959 us; speedup vs baseline: 1.9642x; 1.0207x over previous
//
#include <hip/hip_runtime.h>
#include <stdint.h>
#include <stddef.h>

#define B_    64
#define T_    16
#define DF_   512
#define S_    196
#define DIN_  512
#define H_    8
#define DH_   64
#define DM_   1024
#define MEM_  25
#define HN_   32
#define MR_   (B_*S_)     /* 12544 rows per tick */
#define TC_   4           /* ticks per chunk */
#define MCC_  (MR_*TC_)   /* 50176 rows per chunk */

typedef short bf16x8 __attribute__((ext_vector_type(8)));
typedef short short4v __attribute__((ext_vector_type(4)));
typedef float f32x4  __attribute__((ext_vector_type(4)));

__device__ __forceinline__ float b2f(short h){
  unsigned u = ((unsigned)(unsigned short)h) << 16;
  float f; __builtin_memcpy(&f, &u, 4); return f;
}
__device__ __forceinline__ short f2b(float f){
  unsigned u; __builtin_memcpy(&u, &f, 4);
  u = (u + 0x7fffu + ((u >> 16) & 1u)) >> 16;
  return (short)(unsigned short)u;
}
__device__ __forceinline__ float clip015(float d){
  return d < 0.f ? 0.f : (d > 15.f ? 15.f : d);
}

// ---------------------------------------------------------------------------
// bf16 MFMA GEMM body (verified R8 code). 128x128 tile, BK=64, 4 waves 2x2
// over tid 0..255, 16x16x32 MFMA, global_load_lds width-16, XOR chunk
// swizzle. aload=0 lets a twin block skip A-tile loads (shared lA).
// LNEPI=0: +bias. LNEPI=2: transposed-LN fold (col stats, row gw/bw).
// No spins / unbounded waits anywhere in this file: every kernel terminates.
// ---------------------------------------------------------------------------
template<int OUTF32, int LNEPI>
__device__ __forceinline__ void gemm_body(int tid, int bx, int by, int aload,
    short* lA, short* lB,
    const short* __restrict__ A, const short* __restrict__ WT,
    void* __restrict__ Cout,
    const float* __restrict__ biasA, const float* __restrict__ biasB, int nsplit,
    const float* __restrict__ mu, const float* __restrict__ iv,
    const float* __restrict__ gw, const float* __restrict__ bw,
    int M, int N, int K, int lda, int ldc)
{
  const int w = tid >> 6, l = tid & 63;
  const int m0 = bx * 128, n0 = by * 128;
  const int wm = (w >> 1) * 64, wn = (w & 1) * 64;
  f32x4 acc[4][4];
  #pragma unroll
  for (int i=0;i<4;i++)
    #pragma unroll
    for (int j=0;j<4;j++) acc[i][j] = (f32x4){0.f,0.f,0.f,0.f};

  for (int k0 = 0; k0 < K; k0 += 64) {
    #pragma unroll
    for (int rnd = 0; rnd < 4; ++rnd) {
      int cb = (rnd*4 + w) * 64;
      int slot = cb + l;
      int row = slot >> 3, kb = slot & 7;
      int kc = k0 + ((kb ^ (row & 7)) << 3);
      if (aload) {
        int gm = m0 + row; if (gm > M-1) gm = M-1;
        __builtin_amdgcn_global_load_lds(
            (const __attribute__((address_space(1))) void*)(A + (size_t)gm * lda + kc),
            (__attribute__((address_space(3))) void*)&lA[cb*8], 16, 0, 0);
      }
      __builtin_amdgcn_global_load_lds(
          (const __attribute__((address_space(1))) void*)(WT + (size_t)(n0 + row) * K + kc),
          (__attribute__((address_space(3))) void*)&lB[cb*8], 16, 0, 0);
    }
    asm volatile("s_waitcnt vmcnt(0)" ::: "memory");
    __syncthreads();
    #pragma unroll
    for (int ks = 0; ks < 2; ++ks) {
      bf16x8 af[4], bfr[4];
      #pragma unroll
      for (int i = 0; i < 4; ++i) {
        int ra = wm + i*16 + (l & 15);
        int c  = ks*4 + (l >> 4);
        af[i]  = *(const bf16x8*)&lA[ra*64 + ((c ^ (ra & 7)) << 3)];
        int rb = wn + i*16 + (l & 15);
        bfr[i] = *(const bf16x8*)&lB[rb*64 + ((c ^ (rb & 7)) << 3)];
      }
      #pragma unroll
      for (int i = 0; i < 4; ++i)
        #pragma unroll
        for (int j = 0; j < 4; ++j)
          acc[i][j] = __builtin_amdgcn_mfma_f32_16x16x32_bf16(af[i], bfr[j], acc[i][j], 0, 0, 0);
    }
    __syncthreads();
  }
  #pragma unroll
  for (int i = 0; i < 4; ++i) {
    #pragma unroll
    for (int j = 0; j < 4; ++j) {
      int gn = n0 + wn + j*16 + (l & 15);
      float ivn = 0.f, mun = 0.f, bb = 0.f;
      if (LNEPI == 2) { ivn = iv[gn]; mun = mu[gn]; }
      else bb = biasA ? ((gn < nsplit) ? biasA[gn] : biasB[gn - nsplit]) : 0.f;
      #pragma unroll
      for (int r = 0; r < 4; ++r) {
        int gm = m0 + wm + i*16 + (l >> 4)*4 + r;
        if (gm < M) {
          float v;
          if (LNEPI == 2) v = ivn*(acc[i][j][r] - mun*gw[gm]) + bw[gm];
          else            v = acc[i][j][r] + bb;
          if (OUTF32) ((float*)Cout)[(size_t)gm * ldc + gn] = v;
          else        ((short*)Cout)[(size_t)gm * ldc + gn] = f2b(v);
        }
      }
    }
  }
}

// Standalone 256-thread GEMM kernel (weight prep + chunk-0 pipeline).
template<int OUTF32, int LNEPI>
__global__ __launch_bounds__(256,2) void gemm_k(
    const short* __restrict__ A, const short* __restrict__ WT,
    void* __restrict__ Cout,
    const float* __restrict__ biasA, const float* __restrict__ biasB, int nsplit,
    const float* __restrict__ mu, const float* __restrict__ iv,
    const float* __restrict__ gw, const float* __restrict__ bw,
    int M, int N, int K, int lda, int ldc)
{
  __shared__ short lA[128*64];
  __shared__ short lB[128*64];
  gemm_body<OUTF32,LNEPI>(threadIdx.x, blockIdx.x, blockIdx.y, 1, lA, lB,
                          A, WT, Cout, biasA, biasB, nsplit, mu, iv, gw, bw,
                          M, N, K, lda, ldc);
}

// ---------------------------------------------------------------------------
// Piggyback dispatcher: extra blocks of stage kernels run slices of the NEXT
// chunk's pipeline. op1 = kv-GEMM twin-pair (shared A tile, by split),
// op2 = ln_stats (64 rows/block), op3 = KVT-GEMM twin-pair.
// Coverage exactness: op1 = 4 launches x 196 pairs = 784 = 392bx x 2byp;
// op2 = 784 blocks x 64 rows = 50176; op3 = 7 x 224 = 1568 = 8bx x 196byp.
// ---------------------------------------------------------------------------
__device__ __forceinline__ void run_piggy(int tid, int pb, int pop, int poff,
    char* pool,
    const short* __restrict__ xTn, const short* __restrict__ WkvT,
    const float* __restrict__ bkv,
    short* __restrict__ kvpN, float* __restrict__ muN, float* __restrict__ ivN,
    const short* __restrict__ WkkvT, const float* __restrict__ gw,
    const float* __restrict__ bw, short* __restrict__ KVTN, int McN)
{
  if (pop == 1) {
    int twin = tid >> 8;
    short* lA = (short*)pool;
    short* lB = (short*)(pool + 16384 + 16384*twin);
    int p = poff + pb; if (p > 783) p = 783;
    int bx = p % 392, byp = p / 392;
    gemm_body<0,0>(tid & 255, bx, byp*2 + twin, twin == 0, lA, lB,
                   xTn, WkvT, kvpN, bkv, bkv, 1 << 30,
                   nullptr, nullptr, nullptr, nullptr,
                   McN, 512, 512, 512, 512);
  } else if (pop == 2) {
    int blk = poff + pb;
    int w = tid >> 6, l = tid & 63;
    for (int i = 0; i < 8; ++i) {
      int r = blk*64 + i*8 + w;
      if (r < McN) {
        bf16x8 v8 = *(const bf16x8*)&kvpN[(size_t)r*512 + l*8];
        float s = 0.f, s2 = 0.f;
        #pragma unroll
        for (int j = 0; j < 8; ++j) { float v = b2f(v8[j]); s += v; s2 += v*v; }
        #pragma unroll
        for (int m = 1; m < 64; m <<= 1) { s += __shfl_xor(s, m, 64); s2 += __shfl_xor(s2, m, 64); }
        if (l == 0) {
          float mean = s * (1.f/512.f);
          float var  = s2 * (1.f/512.f) - mean*mean;
          muN[r] = mean;
          ivN[r] = rsqrtf(var + 1e-5f);
        }
      }
    }
  } else if (pop == 3) {
    int twin = tid >> 8;
    short* lA = (short*)pool;
    short* lB = (short*)(pool + 16384 + 16384*twin);
    int p = poff + pb; if (p > 1567) p = 1567;
    int bx = p % 8, byp = p / 8;
    gemm_body<0,2>(tid & 255, bx, byp*2 + twin, twin == 0, lA, lB,
                   WkkvT, kvpN, KVTN, nullptr, nullptr, 0,
                   muN, ivN, gw, bw, 1024, McN, 512, 512, McN);
  }
}

// ---------------------------------------------------------------------------
// Tick bodies (verified R8 logic, pool-based LDS).
// ---------------------------------------------------------------------------
__device__ __forceinline__ void attn_body(int b, int tid, float* smem,
    const float* actT, float* aa, float* ba,
    const int* li_a, const int* ri_a, const float* decay_a,
    const short* WqqB, const float* bqh,
    const short* KVT, int ldkv, int ti, short* preb)
{
  float* syncL = smem;
  float* qhL   = smem + 512;
  float* pL    = smem + 1024;   // 8*256
  int j = tid;
  float rr = expf(-clip015(decay_a[j]));
  float prod = actT[li_a[j]*64 + b] * actT[ri_a[j]*64 + b];
  float a2 = rr*aa[b*512+j] + prod; aa[b*512+j] = a2;
  float bb2 = rr*ba[b*512+j] + 1.f;  ba[b*512+j] = bb2;
  syncL[j] = a2 * rsqrtf(bb2);
  __syncthreads();
  float qa = bqh[j];
  #pragma unroll 8
  for (int k = 0; k < 512; ++k) qa += syncL[k]*b2f(WqqB[k*512+j]);
  qhL[j] = qa;
  __syncthreads();
  int h = tid >> 6, l = tid & 63;
  const size_t cb = (size_t)(ti*B_ + b) * S_;
  const short* Kb = KVT + (size_t)(h*64)*ldkv + cb;
  int s3 = 192 + l; int s3c = s3 < S_ ? s3 : S_-1;
  float sc0=0.f, sc1=0.f, sc2=0.f, sc3=0.f;
  #pragma unroll 8
  for (int d = 0; d < 64; ++d) {
    const short* kr = Kb + (size_t)d*ldkv;
    float qv = qhL[h*64 + d];
    sc0 += qv * b2f(kr[l]);
    sc1 += qv * b2f(kr[64 + l]);
    sc2 += qv * b2f(kr[128 + l]);
    sc3 += qv * b2f(kr[s3c]);
  }
  sc0 *= 0.125f; sc1 *= 0.125f; sc2 *= 0.125f;
  sc3 = (s3 < S_) ? sc3*0.125f : -1e30f;
  float mx = fmaxf(fmaxf(sc0, sc1), fmaxf(sc2, sc3));
  #pragma unroll
  for (int k = 32; k >= 1; k >>= 1) mx = fmaxf(mx, __shfl_xor(mx, k, 64));
  float p0 = expf(sc0-mx), p1 = expf(sc1-mx), p2 = expf(sc2-mx), p3 = expf(sc3-mx);
  pL[h*256 + l] = p0; pL[h*256 + 64+l] = p1;
  pL[h*256 + 128+l] = p2; pL[h*256 + 192+l] = p3;
  float ps = p0+p1+p2+p3;
  #pragma unroll
  for (int k = 32; k >= 1; k >>= 1) ps += __shfl_xor(ps, k, 64);
  float inv = 1.f / ps;
  __syncthreads();
  const short4v* vrow = (const short4v*)(KVT + (size_t)(512 + h*64 + l)*ldkv + cb);
  const float* pp = pL + h*256;
  float ac0=0.f, ac1=0.f, ac2=0.f, ac3=0.f;
  #pragma unroll 7
  for (int c = 0; c < 49; ++c) {
    short4v v4 = vrow[c];
    ac0 += pp[c*4]   * b2f(v4.x);
    ac1 += pp[c*4+1] * b2f(v4.y);
    ac2 += pp[c*4+2] * b2f(v4.z);
    ac3 += pp[c*4+3] * b2f(v4.w);
  }
  float accv = (ac0+ac1)+(ac2+ac3);
  preb[(size_t)b*1536 + h*64 + l] = f2b(accv * inv);
}

__device__ __forceinline__ void outk_body(int tt, int b, int tid,
    float* syncL, float* wred,
    const float* actT, float* ao, float* bo_s,
    const int* li_o, const int* ri_o, const float* decay_o,
    const short* WoutB, const float* bout, float* out)
{
  int j = tid;
  float rr = expf(-clip015(decay_o[j]));
  float prod = actT[li_o[j]*64 + b] * actT[ri_o[j]*64 + b];
  float a2 = rr*ao[b*512+j] + prod; ao[b*512+j] = a2;
  float bb2 = rr*bo_s[b*512+j] + 1.f; bo_s[b*512+j] = bb2;
  syncL[j] = a2 * rsqrtf(bb2);
  __syncthreads();
  float a = bout[j];
  #pragma unroll 8
  for (int k = 0; k < 512; ++k) a += syncL[k]*b2f(WoutB[k*512+j]);
  out[((size_t)b*512 + j)*16 + tt] = a;
  int w = tid >> 6, l = tid & 63;
  float m = a;
  #pragma unroll
  for (int k = 32; k >= 1; k >>= 1) m = fmaxf(m, __shfl_xor(m, k, 64));
  if (l == 0) wred[w] = m;
  __syncthreads();
  float M = wred[0];
  #pragma unroll
  for (int k = 1; k < 8; ++k) M = fmaxf(M, wred[k]);
  float e = expf(a - M);
  float z = e, s1 = e*(a - M);
  #pragma unroll
  for (int k = 32; k >= 1; k >>= 1) { z += __shfl_xor(z, k, 64); s1 += __shfl_xor(s1, k, 64); }
  if (l == 0) { wred[8+w] = z; wred[16+w] = s1; }
  __syncthreads();
  if (tid == 0) {
    float Z = 0.f, S1 = 0.f;
    #pragma unroll
    for (int k = 0; k < 8; ++k) { Z += wred[8+k]; S1 += wred[16+k]; }
    float plp = S1 / Z - logf(Z);
    float ne = -plp * (1.f/logf(512.f));
    out[524288 + (size_t)b*32 + tt]      = ne;
    out[524288 + (size_t)b*32 + 16 + tt] = 1.f - ne;
  }
}

__device__ __forceinline__ void synglu_body(int bid, int tid, char* pool,
    const short* preb, const short* WsynP, const float* bsynF, float* u)
{
  f32x4* part = (f32x4*)pool;
  int w = tid >> 6, l = tid & 63;
  int mf = w & 3, kh = w >> 2;
  int arow = mf*16 + (l & 15);
  int kbase = kh*768 + (l >> 4)*8;
  const short* ap = preb + (size_t)arow*1536 + kbase;
  const short* bp = WsynP + (size_t)(bid*16 + (l & 15))*1536 + kbase;
  f32x4 acc = (f32x4){0.f,0.f,0.f,0.f};
  #pragma unroll 4
  for (int ks = 0; ks < 24; ++ks) {
    bf16x8 av = *(const bf16x8*)(ap + ks*32);
    bf16x8 bv = *(const bf16x8*)(bp + ks*32);
    acc = __builtin_amdgcn_mfma_f32_16x16x32_bf16(av, bv, acc, 0, 0, 0);
  }
  part[w*64 + l] = acc;
  __syncthreads();
  if (w < 4) {
    f32x4 o1 = part[w*64 + l], o2 = part[(w+4)*64 + l];
    int c = l & 15;
    int colg = bid*8 + (c & 7);
    float bias = (c < 8) ? bsynF[colg] : bsynF[1024 + colg];
    float tv[4], pv[4];
    #pragma unroll
    for (int r2 = 0; r2 < 4; ++r2) tv[r2] = o1[r2] + o2[r2] + bias;
    #pragma unroll
    for (int r2 = 0; r2 < 4; ++r2) pv[r2] = __shfl_xor(tv[r2], 8, 64);
    if (c < 8) {
      #pragma unroll
      for (int r2 = 0; r2 < 4; ++r2) {
        float uu = tv[r2] * (1.f/(1.f + expf(-pv[r2])));
        int brow = w*16 + (l >> 4)*4 + r2;
        u[brow*1024 + colg] = uu;
      }
    }
  }
}

__device__ __forceinline__ void nlmln_body(int bid, int tid, char* pool,
    const float* u, const float* gsyn, const float* bln, float* hist,
    const float* W1, const float* b1, const float* W2, const float* b2,
    float* actT, short* preb, int t)
{
  float* mstat = (float*)pool;
  float* istat = mstat + 64;
  {
    int b = tid >> 3, p = tid & 7;
    const float* up = u + b*1024 + p*128;
    float s = 0.f, s2 = 0.f;
    #pragma unroll 8
    for (int i = 0; i < 128; ++i) { float v = up[i]; s += v; s2 += v*v; }
    #pragma unroll
    for (int k = 4; k >= 1; k >>= 1) { s += __shfl_xor(s, k, 64); s2 += __shfl_xor(s2, k, 64); }
    if (p == 0) {
      float mean = s * (1.f/1024.f);
      float var  = s2 * (1.f/1024.f) - mean*mean;
      mstat[b] = mean;
      istat[b] = rsqrtf(var + 1e-5f);
    }
  }
  __syncthreads();
  int n = (bid << 3) + (tid >> 6), b = tid & 63;
  float nv = (u[b*1024 + n] - mstat[b]) * istat[b] * gsyn[n] + bln[n];
  int slot = t % MEM_;
  hist[((size_t)n*MEM_ + slot)*64 + b] = nv;
  float h[32];
  #pragma unroll
  for (int j = 0; j < 32; ++j) h[j] = b1[n*32+j];
  #pragma unroll 5
  for (int m = 0; m < MEM_; ++m) {
    int phys = (t + 1 + m) % MEM_;
    float hv = (m == MEM_-1) ? nv : hist[((size_t)n*MEM_ + phys)*64 + b];
    const float* wp = &W1[((size_t)n*MEM_ + m)*32];
    #pragma unroll
    for (int j = 0; j < 32; ++j) h[j] += hv * wp[j];
  }
  float acc = b2[n];
  #pragma unroll
  for (int j = 0; j < 32; ++j) acc += fmaxf(h[j], 0.f) * W2[n*32+j];
  actT[n*64 + b] = acc;
  preb[(size_t)b*1536 + 512 + n] = f2b(acc);
}

// ---------------------------------------------------------------------------
// Stage kernels: blocks 0-127 run the tick stage; blocks >=128 run piggy.
// ---------------------------------------------------------------------------
#define PIGGY_ARGS int pop, int poff, \
    const short* __restrict__ xTn, const short* __restrict__ WkvT, \
    const float* __restrict__ bkv, short* __restrict__ kvpN, \
    float* __restrict__ muN, float* __restrict__ ivN, \
    const short* __restrict__ WkkvT, const float* __restrict__ gw, \
    const float* __restrict__ bw, short* __restrict__ KVTN, int McN
#define PIGGY_CALL run_piggy(tid, (int)blockIdx.x - 128, pop, poff, pool, \
    xTn, WkvT, bkv, kvpN, muN, ivN, WkkvT, gw, bw, KVTN, McN)

__global__ __launch_bounds__(512) void stageA(
    const float* __restrict__ actT,
    float* __restrict__ aa, float* __restrict__ ba,
    const int* __restrict__ li_a, const int* __restrict__ ri_a,
    const float* __restrict__ decay_a,
    const short* __restrict__ WqqB, const float* __restrict__ bqh,
    const short* __restrict__ KVT, int ldkv, int ti,
    short* __restrict__ preb,
    float* __restrict__ ao, float* __restrict__ bo_s,
    const int* __restrict__ li_o, const int* __restrict__ ri_o,
    const float* __restrict__ decay_o,
    const short* __restrict__ WoutB, const float* __restrict__ bout,
    float* __restrict__ out, int t, PIGGY_ARGS)
{
  __shared__ __attribute__((aligned(16))) char pool[49152];
  const int bid = blockIdx.x, tid = threadIdx.x;
  if (bid < 128) {
    float* smem = (float*)pool;
    if (bid < 64)
      attn_body(bid, tid, smem, actT, aa, ba, li_a, ri_a, decay_a,
                WqqB, bqh, KVT, ldkv, ti, preb);
    else if (t > 0)
      outk_body(t-1, bid-64, tid, smem, smem+512, actT, ao, bo_s,
                li_o, ri_o, decay_o, WoutB, bout, out);
  } else {
    PIGGY_CALL;
  }
}

__global__ __launch_bounds__(512) void stageB(
    const short* __restrict__ preb, const short* __restrict__ WsynP,
    const float* __restrict__ bsynF, float* __restrict__ u, PIGGY_ARGS)
{
  __shared__ __attribute__((aligned(16))) char pool[49152];
  const int bid = blockIdx.x, tid = threadIdx.x;
  if (bid < 128) synglu_body(bid, tid, pool, preb, WsynP, bsynF, u);
  else PIGGY_CALL;
}

__global__ __launch_bounds__(512) void stageC(
    const float* __restrict__ u, const float* __restrict__ gsyn,
    const float* __restrict__ bln, float* __restrict__ hist,
    const float* __restrict__ W1, const float* __restrict__ b1,
    const float* __restrict__ W2, const float* __restrict__ b2,
    float* __restrict__ actT, short* __restrict__ preb, int t, PIGGY_ARGS)
{
  __shared__ __attribute__((aligned(16))) char pool[49152];
  const int bid = blockIdx.x, tid = threadIdx.x;
  if (bid < 128) nlmln_body(bid, tid, pool, u, gsyn, bln, hist,
                            W1, b1, W2, b2, actT, preb, t);
  else PIGGY_CALL;
}

// Final outk for t = T-1.
__global__ __launch_bounds__(512) void outk_fin(
    const float* __restrict__ actT,
    float* __restrict__ ao, float* __restrict__ bo_s,
    const int* __restrict__ li_o, const int* __restrict__ ri_o,
    const float* __restrict__ decay_o,
    const short* __restrict__ WoutB, const float* __restrict__ bout,
    float* __restrict__ out)
{
  __shared__ __attribute__((aligned(16))) float smem[544];
  outk_body(T_-1, blockIdx.x, threadIdx.x, smem, smem+512, actT, ao, bo_s,
            li_o, ri_o, decay_o, WoutB, bout, out);
}

// ---------------------------------------------------------------------------
// Batched transpose of x (ALL ticks): f32 [B][T][DF][S] -> bf16 rows
// ((t*B+b)*S + s) x [DF].
// ---------------------------------------------------------------------------
__global__ __launch_bounds__(256) void xpose_x(const float* __restrict__ x,
                                               short* __restrict__ xT)
{
  __shared__ float tile[32][33];
  int df0 = blockIdx.x*32, s0 = blockIdx.y*32;
  int z = blockIdx.z;
  int b = z / T_, t = z % T_;
  int tx = threadIdx.x & 31, ty = threadIdx.x >> 5;
  const float* src = x + (size_t)(b*T_ + t) * DF_ * S_;
  #pragma unroll
  for (int i = 0; i < 4; ++i) {
    int df = df0 + ty + i*8;
    int s  = s0 + tx;
    tile[ty+i*8][tx] = (s < S_) ? src[(size_t)df*S_ + s] : 0.f;
  }
  __syncthreads();
  short* dst = xT + (size_t)(t*B_ + b) * S_ * DIN_;
  #pragma unroll
  for (int i = 0; i < 4; ++i) {
    int s  = s0 + ty + i*8;
    int df = df0 + tx;
    if (s < S_) dst[(size_t)s*DF_ + df] = f2b(tile[tx][ty+i*8]);
  }
}

// Weight transpose f32->bf16, optional per-row scale.
__global__ __launch_bounds__(256) void wtrans(const float* __restrict__ in,
    short* __restrict__ out, int R, int C, int ldo, int coff,
    const float* __restrict__ scale)
{
  __shared__ float tile[32][33];
  int c0 = blockIdx.x*32, r0 = blockIdx.y*32;
  int tx = threadIdx.x & 31, ty = threadIdx.x >> 5;
  #pragma unroll
  for (int i = 0; i < 4; ++i) {
    int r = r0+ty+i*8;
    float sc = scale ? scale[r] : 1.f;
    tile[ty+i*8][tx] = in[(size_t)r*C + c0+tx] * sc;
  }
  __syncthreads();
  #pragma unroll
  for (int i = 0; i < 4; ++i)
    out[(size_t)(c0+ty+i*8)*ldo + coff + r0+tx] = f2b(tile[tx][ty+i*8]);
}

__global__ __launch_bounds__(256) void cvtb(const float* __restrict__ in,
                                            short* __restrict__ out, int n)
{
  int i = blockIdx.x*256 + threadIdx.x;
  if (i < n) out[i] = f2b(in[i]);
}

__global__ __launch_bounds__(256) void bias_fold(const float* __restrict__ vec,
    const float* __restrict__ W, const float* __restrict__ base,
    float* __restrict__ out, int N, int ldw)
{
  int n = blockIdx.x*256 + threadIdx.x;
  if (n >= N) return;
  float a = base ? base[n] : 0.f;
  #pragma unroll 8
  for (int k = 0; k < 512; ++k) a += vec[k]*W[(size_t)k*ldw + n];
  out[n] = a;
}

__global__ __launch_bounds__(256) void permrows(const short* __restrict__ in,
                                                short* __restrict__ out)
{
  int r = blockIdx.x;
  int k = r >> 4, i = r & 15;
  int src = (i < 8) ? (k*8 + i) : (1024 + k*8 + (i - 8));
  const bf16x8* s = (const bf16x8*)(in + (size_t)src*1536);
  bf16x8* d = (bf16x8*)(out + (size_t)r*1536);
  int j = threadIdx.x;
  if (j < 192) d[j] = s[j];
}

// Standalone per-row LN stats (chunk 0 / fallback).
__global__ __launch_bounds__(256) void ln_stats(const short* __restrict__ in,
    float* __restrict__ mu, float* __restrict__ iv, int nrows)
{
  int w = threadIdx.x >> 6, l = threadIdx.x & 63;
  int r = blockIdx.x*4 + w;
  if (r >= nrows) return;
  bf16x8 v8 = *(const bf16x8*)&in[(size_t)r*512 + l*8];
  float s = 0.f, s2 = 0.f;
  #pragma unroll
  for (int j = 0; j < 8; ++j) { float v = b2f(v8[j]); s += v; s2 += v*v; }
  #pragma unroll
  for (int m = 1; m < 64; m <<= 1) { s += __shfl_xor(s, m, 64); s2 += __shfl_xor(s2, m, 64); }
  if (l == 0) {
    float mean = s * (1.f/512.f);
    float var  = s2 * (1.f/512.f) - mean*mean;
    mu[r] = mean;
    iv[r] = rsqrtf(var + 1e-5f);
  }
}

// Re-initialize all recurrent state (graph-replay deterministic).
__global__ __launch_bounds__(256) void initk(float* __restrict__ aa, float* __restrict__ ba,
    float* __restrict__ ao, float* __restrict__ bo_s,
    float* __restrict__ actT, float* __restrict__ hist, short* __restrict__ preb,
    const float* __restrict__ init_act, const float* __restrict__ init_hist,
    const int* __restrict__ li_o, const int* __restrict__ ri_o)
{
  int i = blockIdx.x*256 + threadIdx.x;
  if (i < 64*512) {
    aa[i] = 0.f; ba[i] = 0.f;
    int j = i & 511;
    ao[i] = init_act[li_o[j]] * init_act[ri_o[j]];
    bo_s[i] = 1.f;
  }
  if (i < 65536) {
    int n = i >> 6, b = i & 63;
    actT[i] = init_act[n];
    preb[(size_t)b*1536 + 512 + n] = f2b(init_act[n]);
  }
  if (i < DM_*MEM_*64) {
    int nm = i >> 6;
    hist[i] = init_hist[nm];
  }
}

// ---------------------------------------------------------------------------
extern "C" void kernel_launch(void* const* d_in, const int* in_sizes, int n_in,
                              void* d_out, int out_size, void* d_ws, size_t ws_size,
                              hipStream_t stream)
{
  (void)in_sizes; (void)n_in; (void)out_size;
  const float* x       = (const float*)d_in[0];
  const float* Wqp     = (const float*)d_in[1];
  const float* bqp     = (const float*)d_in[2];
  const float* Wkv     = (const float*)d_in[3];
  const float* bkv     = (const float*)d_in[4];
  const float* g_kv    = (const float*)d_in[5];
  const float* b_kv    = (const float*)d_in[6];
  const float* Wq      = (const float*)d_in[7];
  const float* bq      = (const float*)d_in[8];
  const float* Wk      = (const float*)d_in[9];
  const float* bk      = (const float*)d_in[10];
  const float* Wv      = (const float*)d_in[11];
  const float* bv      = (const float*)d_in[12];
  const float* Wo      = (const float*)d_in[13];
  const float* bo_p    = (const float*)d_in[14];
  const float* Wsyn    = (const float*)d_in[15];
  const float* bsyn    = (const float*)d_in[16];
  const float* g_syn   = (const float*)d_in[17];
  const float* b_syn   = (const float*)d_in[18];
  const float* W1      = (const float*)d_in[19];
  const float* b1      = (const float*)d_in[20];
  const float* W2      = (const float*)d_in[21];
  const float* b2      = (const float*)d_in[22];
  const float* init_act  = (const float*)d_in[23];
  const float* init_hist = (const float*)d_in[24];
  const float* decay_a = (const float*)d_in[25];
  const float* decay_o = (const float*)d_in[26];
  const float* Wout    = (const float*)d_in[27];
  const float* bout    = (const float*)d_in[28];
  const int* li_a = (const int*)d_in[29];
  const int* ri_a = (const int*)d_in[30];
  const int* li_o = (const int*)d_in[31];
  const int* ri_o = (const int*)d_in[32];

  char* ws = (char*)d_ws;
  size_t off = 0;
  auto alloc = [&](size_t bytes) { char* p = ws + off; off += (bytes + 255) & ~(size_t)255; return p; };
  short* WkvT   = (short*)alloc(512*512*2);
  short* WkkvT  = (short*)alloc(1024*512*2);
  short* WsynF  = (short*)alloc(2048*1536*2);
  short* WsynP  = (short*)alloc(2048*1536*2);
  short* WsynTt = (short*)alloc(2048*512*2);
  short* WqpB   = (short*)alloc(512*512*2);
  short* WqT    = (short*)alloc(512*512*2);
  short* WoB    = (short*)alloc(512*512*2);
  short* WqqB   = (short*)alloc(512*512*2);
  short* WoutB  = (short*)alloc(512*512*2);
  float* bqh    = (float*)alloc(512*4);
  float* bsynF  = (float*)alloc(2048*4);
  float* gw     = (float*)alloc(1024*4);
  float* bw     = (float*)alloc(1024*4);
  short* preb   = (short*)alloc(64*1536*2);
  float* u      = (float*)alloc(64*1024*4);
  float* aa     = (float*)alloc(64*512*4);
  float* ba     = (float*)alloc(64*512*4);
  float* ao     = (float*)alloc(64*512*4);
  float* bo_s   = (float*)alloc(64*512*4);
  float* actT   = (float*)alloc(1024*64*4);
  float* hist   = (float*)alloc((size_t)1024*25*64*4);
  size_t fixed_end = off;

  const size_t szXT  = (size_t)T_*MR_*512*2;     // 205.5 MB (all 16 ticks)
  const size_t szKVP = (size_t)MCC_*512*2;       //  51.4 MB per chunk
  const size_t szKVT = (size_t)MCC_*1024*2;      // 102.8 MB per chunk
  const size_t szST  = (size_t)MCC_*4;           //   0.2 MB
  size_t need_full = fixed_end + szXT + 2*szKVP + 2*szKVT + 4*szST + 4096;
  bool pig_en = (ws_size >= need_full);

  short* xT = (short*)alloc(szXT);
  short* kvpB[2]; short* KVTB[2]; float* muB[2]; float* ivB[2];
  kvpB[0] = (short*)alloc(szKVP);
  KVTB[0] = (short*)alloc(szKVT);
  muB[0]  = (float*)alloc(szST);
  ivB[0]  = (float*)alloc(szST);
  if (pig_en) {
    kvpB[1] = (short*)alloc(szKVP);
    KVTB[1] = (short*)alloc(szKVT);
    muB[1]  = (float*)alloc(szST);
    ivB[1]  = (float*)alloc(szST);
  } else {
    kvpB[1] = kvpB[0]; KVTB[1] = KVTB[0]; muB[1] = muB[0]; ivB[1] = ivB[0];
  }

  const int BIG = 1 << 30;
  const float* FN = nullptr;

  initk<<<6400, 256, 0, stream>>>(aa, ba, ao, bo_s, actT, hist, preb,
                                  init_act, init_hist, li_o, ri_o);
  wtrans<<<dim3(16,16), 256, 0, stream>>>(Wkv, WkvT, 512, 512, 512, 0, nullptr);
  wtrans<<<dim3(16,16), 256, 0, stream>>>(Wk,  WkkvT, 512, 512, 512, 0, g_kv);
  wtrans<<<dim3(16,16), 256, 0, stream>>>(Wv,  WkkvT + (size_t)512*512, 512, 512, 512, 0, g_kv);
  wtrans<<<dim3(64,32), 256, 0, stream>>>(Wsyn + (size_t)512*2048, WsynF, 1024, 2048, 1536, 512, nullptr);
  wtrans<<<dim3(64,16), 256, 0, stream>>>(Wsyn, WsynTt, 512, 2048, 512, 0, nullptr);
  wtrans<<<dim3(16,16), 256, 0, stream>>>(Wq,  WqT, 512, 512, 512, 0, nullptr);
  cvtb<<<1024, 256, 0, stream>>>(Wqp, WqpB, 512*512);
  cvtb<<<1024, 256, 0, stream>>>(Wo,  WoB,  512*512);
  cvtb<<<1024, 256, 0, stream>>>(Wout, WoutB, 512*512);
  gemm_k<0,0><<<dim3(4,4), 256, 0, stream>>>(WqpB, WqT, WqqB, nullptr, nullptr, BIG,
                                             FN, FN, FN, FN, 512, 512, 512, 512, 512);
  gemm_k<0,0><<<dim3(16,4), 256, 0, stream>>>(WsynTt, WoB, WsynF, nullptr, nullptr, BIG,
                                              FN, FN, FN, FN, 2048, 512, 512, 512, 1536);
  permrows<<<2048, 256, 0, stream>>>(WsynF, WsynP);
  bias_fold<<<2, 256, 0, stream>>>(bqp,  Wq,   bq,   bqh,   512,  512);
  bias_fold<<<8, 256, 0, stream>>>(bo_p, Wsyn, bsyn, bsynF, 2048, 2048);
  bias_fold<<<2, 256, 0, stream>>>(g_kv, Wk, nullptr, gw,       512, 512);
  bias_fold<<<2, 256, 0, stream>>>(g_kv, Wv, nullptr, gw + 512, 512, 512);
  bias_fold<<<2, 256, 0, stream>>>(b_kv, Wk, bk, bw,       512, 512);
  bias_fold<<<2, 256, 0, stream>>>(b_kv, Wv, bv, bw + 512, 512, 512);

  // transpose all 16 ticks of x up front
  xpose_x<<<dim3(16,7,B_*T_), 256, 0, stream>>>(x, xT);

  auto run_pipe = [&](int c, short* kvpP, float* muP, float* ivP, short* KVTP){
    const short* xTc = xT + (size_t)c*TC_*MR_*512;
    gemm_k<0,0><<<dim3(392,4), 256, 0, stream>>>(xTc, WkvT, kvpP, bkv, bkv, BIG,
                                                 FN, FN, FN, FN, MCC_, 512, 512, 512, 512);
    ln_stats<<<MCC_/4, 256, 0, stream>>>(kvpP, muP, ivP, MCC_);
    gemm_k<0,2><<<dim3(8,392), 256, 0, stream>>>(WkkvT, kvpP, KVTP, nullptr, nullptr, BIG,
                                                 muP, ivP, gw, bw, 1024, MCC_, 512, 512, MCC_);
  };

  auto pigcfg = [](int q, bool pig, int& op, int& pf, int& n){
    op = 0; pf = 0; n = 0;
    if (!pig) return;
    if (q < 4)      { op = 1; pf = q*196;     n = 196; }
    else if (q == 4){ op = 2; pf = 0;         n = 784; }
    else            { op = 3; pf = (q-5)*224; n = 224; }
  };

  run_pipe(0, kvpB[0], muB[0], ivB[0], KVTB[0]);

  for (int c = 0; c < 4; ++c) {
    int par = pig_en ? (c & 1) : 0;
    int nxt = pig_en ? (par ^ 1) : 0;
    if (!pig_en && c > 0) run_pipe(c, kvpB[0], muB[0], ivB[0], KVTB[0]);
    bool pig = pig_en && (c < 3);
    const short* xTn = (c < 3) ? xT + (size_t)(c+1)*TC_*MR_*512 : xT;
    for (int ti = 0; ti < TC_; ++ti) {
      int t = c*TC_ + ti;
      int op, pf, n;
      pigcfg(ti*3+0, pig, op, pf, n);
      stageA<<<128+n, 512, 0, stream>>>(actT, aa, ba, li_a, ri_a, decay_a,
          WqqB, bqh, KVTB[par], MCC_, ti, preb,
          ao, bo_s, li_o, ri_o, decay_o, WoutB, bout, (float*)d_out, t,
          op, pf, xTn, WkvT, bkv, kvpB[nxt], muB[nxt], ivB[nxt],
          WkkvT, gw, bw, KVTB[nxt], MCC_);
      pigcfg(ti*3+1, pig, op, pf, n);
      stageB<<<128+n, 512, 0, stream>>>(preb, WsynP, bsynF, u,
          op, pf, xTn, WkvT, bkv, kvpB[nxt], muB[nxt], ivB[nxt],
          WkkvT, gw, bw, KVTB[nxt], MCC_);
      pigcfg(ti*3+2, pig, op, pf, n);
      stageC<<<128+n, 512, 0, stream>>>(u, g_syn, b_syn, hist,
          W1, b1, W2, b2, actT, preb, t,
          op, pf, xTn, WkvT, bkv, kvpB[nxt], muB[nxt], ivB[nxt],
          WkkvT, gw, bw, KVTB[nxt], MCC_);
    }
  }
  outk_fin<<<64, 512, 0, stream>>>(actT, ao, bo_s, li_o, ri_o, decay_o,
                                   WoutB, bout, (float*)d_out);
}

// Round 11
// 2345.910 us; speedup vs baseline: 2.0455x; 1.0414x over previous
//
#include <hip/hip_runtime.h>
#include <stdint.h>
#include <stddef.h>

#define B_    64
#define T_    16
#define DF_   512
#define S_    196
#define DIN_  512
#define H_    8
#define DH_   64
#define DM_   1024
#define MEM_  25
#define HN_   32
#define MR_   (B_*S_)     /* 12544 rows per tick */
#define TC_   4           /* ticks per chunk */
#define MCC_  (MR_*TC_)   /* 50176 rows per chunk */

typedef short bf16x8 __attribute__((ext_vector_type(8)));
typedef short short4v __attribute__((ext_vector_type(4)));
typedef float f32x4  __attribute__((ext_vector_type(4)));

__device__ __forceinline__ float b2f(short h){
  unsigned u = ((unsigned)(unsigned short)h) << 16;
  float f; __builtin_memcpy(&f, &u, 4); return f;
}
__device__ __forceinline__ short f2b(float f){
  unsigned u; __builtin_memcpy(&u, &f, 4);
  u = (u + 0x7fffu + ((u >> 16) & 1u)) >> 16;
  return (short)(unsigned short)u;
}
__device__ __forceinline__ float clip015(float d){
  return d < 0.f ? 0.f : (d > 15.f ? 15.f : d);
}

// ---------------------------------------------------------------------------
// bf16 MFMA GEMM body (verified R8/R10 code). 128x128 tile, BK=64, 4 waves
// 2x2 over tid 0..255, 16x16x32 MFMA, global_load_lds width-16, XOR chunk
// swizzle. aload=0 lets a twin block skip A-tile loads (shared lA).
// LNEPI=0: +bias. LNEPI=2: transposed-LN fold (col stats, row gw/bw).
// No spins / unbounded waits anywhere in this file: every kernel terminates.
// ---------------------------------------------------------------------------
template<int OUTF32, int LNEPI>
__device__ __forceinline__ void gemm_body(int tid, int bx, int by, int aload,
    short* lA, short* lB,
    const short* __restrict__ A, const short* __restrict__ WT,
    void* __restrict__ Cout,
    const float* __restrict__ biasA, const float* __restrict__ biasB, int nsplit,
    const float* __restrict__ mu, const float* __restrict__ iv,
    const float* __restrict__ gw, const float* __restrict__ bw,
    int M, int N, int K, int lda, int ldc)
{
  const int w = tid >> 6, l = tid & 63;
  const int m0 = bx * 128, n0 = by * 128;
  const int wm = (w >> 1) * 64, wn = (w & 1) * 64;
  f32x4 acc[4][4];
  #pragma unroll
  for (int i=0;i<4;i++)
    #pragma unroll
    for (int j=0;j<4;j++) acc[i][j] = (f32x4){0.f,0.f,0.f,0.f};

  for (int k0 = 0; k0 < K; k0 += 64) {
    #pragma unroll
    for (int rnd = 0; rnd < 4; ++rnd) {
      int cb = (rnd*4 + w) * 64;
      int slot = cb + l;
      int row = slot >> 3, kb = slot & 7;
      int kc = k0 + ((kb ^ (row & 7)) << 3);
      if (aload) {
        int gm = m0 + row; if (gm > M-1) gm = M-1;
        __builtin_amdgcn_global_load_lds(
            (const __attribute__((address_space(1))) void*)(A + (size_t)gm * lda + kc),
            (__attribute__((address_space(3))) void*)&lA[cb*8], 16, 0, 0);
      }
      __builtin_amdgcn_global_load_lds(
          (const __attribute__((address_space(1))) void*)(WT + (size_t)(n0 + row) * K + kc),
          (__attribute__((address_space(3))) void*)&lB[cb*8], 16, 0, 0);
    }
    asm volatile("s_waitcnt vmcnt(0)" ::: "memory");
    __syncthreads();
    #pragma unroll
    for (int ks = 0; ks < 2; ++ks) {
      bf16x8 af[4], bfr[4];
      #pragma unroll
      for (int i = 0; i < 4; ++i) {
        int ra = wm + i*16 + (l & 15);
        int c  = ks*4 + (l >> 4);
        af[i]  = *(const bf16x8*)&lA[ra*64 + ((c ^ (ra & 7)) << 3)];
        int rb = wn + i*16 + (l & 15);
        bfr[i] = *(const bf16x8*)&lB[rb*64 + ((c ^ (rb & 7)) << 3)];
      }
      #pragma unroll
      for (int i = 0; i < 4; ++i)
        #pragma unroll
        for (int j = 0; j < 4; ++j)
          acc[i][j] = __builtin_amdgcn_mfma_f32_16x16x32_bf16(af[i], bfr[j], acc[i][j], 0, 0, 0);
    }
    __syncthreads();
  }
  #pragma unroll
  for (int i = 0; i < 4; ++i) {
    #pragma unroll
    for (int j = 0; j < 4; ++j) {
      int gn = n0 + wn + j*16 + (l & 15);
      float ivn = 0.f, mun = 0.f, bb = 0.f;
      if (LNEPI == 2) { ivn = iv[gn]; mun = mu[gn]; }
      else bb = biasA ? ((gn < nsplit) ? biasA[gn] : biasB[gn - nsplit]) : 0.f;
      #pragma unroll
      for (int r = 0; r < 4; ++r) {
        int gm = m0 + wm + i*16 + (l >> 4)*4 + r;
        if (gm < M) {
          float v;
          if (LNEPI == 2) v = ivn*(acc[i][j][r] - mun*gw[gm]) + bw[gm];
          else            v = acc[i][j][r] + bb;
          if (OUTF32) ((float*)Cout)[(size_t)gm * ldc + gn] = v;
          else        ((short*)Cout)[(size_t)gm * ldc + gn] = f2b(v);
        }
      }
    }
  }
}

// Standalone 256-thread GEMM kernel (weight prep + chunk-0 pipeline).
template<int OUTF32, int LNEPI>
__global__ __launch_bounds__(256,2) void gemm_k(
    const short* __restrict__ A, const short* __restrict__ WT,
    void* __restrict__ Cout,
    const float* __restrict__ biasA, const float* __restrict__ biasB, int nsplit,
    const float* __restrict__ mu, const float* __restrict__ iv,
    const float* __restrict__ gw, const float* __restrict__ bw,
    int M, int N, int K, int lda, int ldc)
{
  __shared__ short lA[128*64];
  __shared__ short lB[128*64];
  gemm_body<OUTF32,LNEPI>(threadIdx.x, blockIdx.x, blockIdx.y, 1, lA, lB,
                          A, WT, Cout, biasA, biasB, nsplit, mu, iv, gw, bw,
                          M, N, K, lda, ldc);
}

// ---------------------------------------------------------------------------
// Piggyback dispatcher. op4 = x-transpose slice (2 twins x 16 tiles/block),
// op1 = kv-GEMM twin-pair, op2 = ln_stats (64 rows/block), op3 = KVT twin-pair.
// Coverage: op4 = 2 x 448 x 32 = 28672 tiles = 16df x 7s x 256(b,ti);
// op1 = 4 x 196 = 784 pairs = 392bx x 2byp; op2 = 784 x 64 rows = 50176;
// op3 = 5 x 314 = 1570 (clamped to 1568) = 8bx x 196byp pairs.
// ---------------------------------------------------------------------------
__device__ __forceinline__ void run_piggy(int tid, int pb, int pop, int poff,
    char* pool,
    const float* __restrict__ xg, int t0n, short* __restrict__ xT,
    const short* __restrict__ WkvT, const float* __restrict__ bkv,
    short* __restrict__ kvpN, float* __restrict__ muN, float* __restrict__ ivN,
    const short* __restrict__ WkkvT, const float* __restrict__ gw,
    const float* __restrict__ bw, short* __restrict__ KVTN, int McN)
{
  if (pop == 4) {
    // piggy xpose: 512 thr = 2 twins x 256 thr; each twin 16 tiles.
    int twin = tid >> 8, tid2 = tid & 255;
    float* tile = (float*)(pool + twin*8448);   // [32][33] f32 + pad
    int tx = tid2 & 31, ty = tid2 >> 5;
    int base = (poff + pb)*32 + twin*16;
    for (int it = 0; it < 16; ++it) {
      int gt = base + it;
      int df0 = (gt & 15) * 32;
      int r = gt >> 4;
      int s0 = (r % 7) * 32;
      int z = r / 7;              // [0,256)
      int b = z >> 2, ti = z & 3;
      const float* src = xg + (size_t)(b*T_ + t0n + ti) * DF_ * S_;
      #pragma unroll
      for (int i = 0; i < 4; ++i) {
        int df = df0 + ty + i*8;
        int s  = s0 + tx;
        tile[(ty+i*8)*33 + tx] = (s < S_) ? src[(size_t)df*S_ + s] : 0.f;
      }
      __syncthreads();
      short* dst = xT + (size_t)((t0n + ti)*B_ + b) * S_ * DIN_;
      #pragma unroll
      for (int i = 0; i < 4; ++i) {
        int s  = s0 + ty + i*8;
        int df = df0 + tx;
        if (s < S_) dst[(size_t)s*DF_ + df] = f2b(tile[tx*33 + ty+i*8]);
      }
      __syncthreads();
    }
  } else if (pop == 1) {
    int twin = tid >> 8;
    short* lA = (short*)pool;
    short* lB = (short*)(pool + 16384 + 16384*twin);
    int p = poff + pb; if (p > 783) p = 783;
    int bx = p % 392, byp = p / 392;
    const short* xTn = xT + (size_t)t0n * MR_ * 512;
    gemm_body<0,0>(tid & 255, bx, byp*2 + twin, twin == 0, lA, lB,
                   xTn, WkvT, kvpN, bkv, bkv, 1 << 30,
                   nullptr, nullptr, nullptr, nullptr,
                   McN, 512, 512, 512, 512);
  } else if (pop == 2) {
    int blk = poff + pb;
    int w = tid >> 6, l = tid & 63;
    for (int i = 0; i < 8; ++i) {
      int r = blk*64 + i*8 + w;
      if (r < McN) {
        bf16x8 v8 = *(const bf16x8*)&kvpN[(size_t)r*512 + l*8];
        float s = 0.f, s2 = 0.f;
        #pragma unroll
        for (int j = 0; j < 8; ++j) { float v = b2f(v8[j]); s += v; s2 += v*v; }
        #pragma unroll
        for (int m = 1; m < 64; m <<= 1) { s += __shfl_xor(s, m, 64); s2 += __shfl_xor(s2, m, 64); }
        if (l == 0) {
          float mean = s * (1.f/512.f);
          float var  = s2 * (1.f/512.f) - mean*mean;
          muN[r] = mean;
          ivN[r] = rsqrtf(var + 1e-5f);
        }
      }
    }
  } else if (pop == 3) {
    int twin = tid >> 8;
    short* lA = (short*)pool;
    short* lB = (short*)(pool + 16384 + 16384*twin);
    int p = poff + pb; if (p > 1567) p = 1567;
    int bx = p % 8, byp = p / 8;
    gemm_body<0,2>(tid & 255, bx, byp*2 + twin, twin == 0, lA, lB,
                   WkkvT, kvpN, KVTN, nullptr, nullptr, 0,
                   muN, ivN, gw, bw, 1024, McN, 512, 512, McN);
  }
}

// ---------------------------------------------------------------------------
// Tick bodies (verified R8/R10 logic, pool-based LDS).
// ---------------------------------------------------------------------------
__device__ __forceinline__ void attn_body(int b, int tid, float* smem,
    const float* actT, float* aa, float* ba,
    const int* li_a, const int* ri_a, const float* decay_a,
    const short* WqqB, const float* bqh,
    const short* KVT, int ldkv, int ti, short* preb)
{
  float* syncL = smem;
  float* qhL   = smem + 512;
  float* pL    = smem + 1024;   // 8*256
  int j = tid;
  float rr = expf(-clip015(decay_a[j]));
  float prod = actT[li_a[j]*64 + b] * actT[ri_a[j]*64 + b];
  float a2 = rr*aa[b*512+j] + prod; aa[b*512+j] = a2;
  float bb2 = rr*ba[b*512+j] + 1.f;  ba[b*512+j] = bb2;
  syncL[j] = a2 * rsqrtf(bb2);
  __syncthreads();
  float qa = bqh[j];
  #pragma unroll 8
  for (int k = 0; k < 512; ++k) qa += syncL[k]*b2f(WqqB[k*512+j]);
  qhL[j] = qa;
  __syncthreads();
  int h = tid >> 6, l = tid & 63;
  const size_t cb = (size_t)(ti*B_ + b) * S_;
  const short* Kb = KVT + (size_t)(h*64)*ldkv + cb;
  int s3 = 192 + l; int s3c = s3 < S_ ? s3 : S_-1;
  float sc0=0.f, sc1=0.f, sc2=0.f, sc3=0.f;
  #pragma unroll 8
  for (int d = 0; d < 64; ++d) {
    const short* kr = Kb + (size_t)d*ldkv;
    float qv = qhL[h*64 + d];
    sc0 += qv * b2f(kr[l]);
    sc1 += qv * b2f(kr[64 + l]);
    sc2 += qv * b2f(kr[128 + l]);
    sc3 += qv * b2f(kr[s3c]);
  }
  sc0 *= 0.125f; sc1 *= 0.125f; sc2 *= 0.125f;
  sc3 = (s3 < S_) ? sc3*0.125f : -1e30f;
  float mx = fmaxf(fmaxf(sc0, sc1), fmaxf(sc2, sc3));
  #pragma unroll
  for (int k = 32; k >= 1; k >>= 1) mx = fmaxf(mx, __shfl_xor(mx, k, 64));
  float p0 = expf(sc0-mx), p1 = expf(sc1-mx), p2 = expf(sc2-mx), p3 = expf(sc3-mx);
  pL[h*256 + l] = p0; pL[h*256 + 64+l] = p1;
  pL[h*256 + 128+l] = p2; pL[h*256 + 192+l] = p3;
  float ps = p0+p1+p2+p3;
  #pragma unroll
  for (int k = 32; k >= 1; k >>= 1) ps += __shfl_xor(ps, k, 64);
  float inv = 1.f / ps;
  __syncthreads();
  const short4v* vrow = (const short4v*)(KVT + (size_t)(512 + h*64 + l)*ldkv + cb);
  const float* pp = pL + h*256;
  float ac0=0.f, ac1=0.f, ac2=0.f, ac3=0.f;
  #pragma unroll 7
  for (int c = 0; c < 49; ++c) {
    short4v v4 = vrow[c];
    ac0 += pp[c*4]   * b2f(v4.x);
    ac1 += pp[c*4+1] * b2f(v4.y);
    ac2 += pp[c*4+2] * b2f(v4.z);
    ac3 += pp[c*4+3] * b2f(v4.w);
  }
  float accv = (ac0+ac1)+(ac2+ac3);
  preb[(size_t)b*1536 + h*64 + l] = f2b(accv * inv);
}

__device__ __forceinline__ void outk_body(int tt, int b, int tid,
    float* syncL, float* wred,
    const float* actT, float* ao, float* bo_s,
    const int* li_o, const int* ri_o, const float* decay_o,
    const short* WoutB, const float* bout, float* out)
{
  int j = tid;
  float rr = expf(-clip015(decay_o[j]));
  float prod = actT[li_o[j]*64 + b] * actT[ri_o[j]*64 + b];
  float a2 = rr*ao[b*512+j] + prod; ao[b*512+j] = a2;
  float bb2 = rr*bo_s[b*512+j] + 1.f; bo_s[b*512+j] = bb2;
  syncL[j] = a2 * rsqrtf(bb2);
  __syncthreads();
  float a = bout[j];
  #pragma unroll 8
  for (int k = 0; k < 512; ++k) a += syncL[k]*b2f(WoutB[k*512+j]);
  out[((size_t)b*512 + j)*16 + tt] = a;
  int w = tid >> 6, l = tid & 63;
  float m = a;
  #pragma unroll
  for (int k = 32; k >= 1; k >>= 1) m = fmaxf(m, __shfl_xor(m, k, 64));
  if (l == 0) wred[w] = m;
  __syncthreads();
  float M = wred[0];
  #pragma unroll
  for (int k = 1; k < 8; ++k) M = fmaxf(M, wred[k]);
  float e = expf(a - M);
  float z = e, s1 = e*(a - M);
  #pragma unroll
  for (int k = 32; k >= 1; k >>= 1) { z += __shfl_xor(z, k, 64); s1 += __shfl_xor(s1, k, 64); }
  if (l == 0) { wred[8+w] = z; wred[16+w] = s1; }
  __syncthreads();
  if (tid == 0) {
    float Z = 0.f, S1 = 0.f;
    #pragma unroll
    for (int k = 0; k < 8; ++k) { Z += wred[8+k]; S1 += wred[16+k]; }
    float plp = S1 / Z - logf(Z);
    float ne = -plp * (1.f/logf(512.f));
    out[524288 + (size_t)b*32 + tt]      = ne;
    out[524288 + (size_t)b*32 + 16 + tt] = 1.f - ne;
  }
}

__device__ __forceinline__ void synglu_body(int bid, int tid, char* pool,
    const short* preb, const short* WsynP, const float* bsynF, float* u)
{
  f32x4* part = (f32x4*)pool;
  int w = tid >> 6, l = tid & 63;
  int mf = w & 3, kh = w >> 2;
  int arow = mf*16 + (l & 15);
  int kbase = kh*768 + (l >> 4)*8;
  const short* ap = preb + (size_t)arow*1536 + kbase;
  const short* bp = WsynP + (size_t)(bid*16 + (l & 15))*1536 + kbase;
  f32x4 acc = (f32x4){0.f,0.f,0.f,0.f};
  #pragma unroll 4
  for (int ks = 0; ks < 24; ++ks) {
    bf16x8 av = *(const bf16x8*)(ap + ks*32);
    bf16x8 bv = *(const bf16x8*)(bp + ks*32);
    acc = __builtin_amdgcn_mfma_f32_16x16x32_bf16(av, bv, acc, 0, 0, 0);
  }
  part[w*64 + l] = acc;
  __syncthreads();
  if (w < 4) {
    f32x4 o1 = part[w*64 + l], o2 = part[(w+4)*64 + l];
    int c = l & 15;
    int colg = bid*8 + (c & 7);
    float bias = (c < 8) ? bsynF[colg] : bsynF[1024 + colg];
    float tv[4], pv[4];
    #pragma unroll
    for (int r2 = 0; r2 < 4; ++r2) tv[r2] = o1[r2] + o2[r2] + bias;
    #pragma unroll
    for (int r2 = 0; r2 < 4; ++r2) pv[r2] = __shfl_xor(tv[r2], 8, 64);
    if (c < 8) {
      #pragma unroll
      for (int r2 = 0; r2 < 4; ++r2) {
        float uu = tv[r2] * (1.f/(1.f + expf(-pv[r2])));
        int brow = w*16 + (l >> 4)*4 + r2;
        u[brow*1024 + colg] = uu;
      }
    }
  }
}

__device__ __forceinline__ void nlmln_body(int bid, int tid, char* pool,
    const float* u, const float* gsyn, const float* bln, float* hist,
    const float* W1, const float* b1, const float* W2, const float* b2,
    float* actT, short* preb, int t)
{
  float* mstat = (float*)pool;
  float* istat = mstat + 64;
  {
    int b = tid >> 3, p = tid & 7;
    const float* up = u + b*1024 + p*128;
    float s = 0.f, s2 = 0.f;
    #pragma unroll 8
    for (int i = 0; i < 128; ++i) { float v = up[i]; s += v; s2 += v*v; }
    #pragma unroll
    for (int k = 4; k >= 1; k >>= 1) { s += __shfl_xor(s, k, 64); s2 += __shfl_xor(s2, k, 64); }
    if (p == 0) {
      float mean = s * (1.f/1024.f);
      float var  = s2 * (1.f/1024.f) - mean*mean;
      mstat[b] = mean;
      istat[b] = rsqrtf(var + 1e-5f);
    }
  }
  __syncthreads();
  int n = (bid << 3) + (tid >> 6), b = tid & 63;
  float nv = (u[b*1024 + n] - mstat[b]) * istat[b] * gsyn[n] + bln[n];
  int slot = t % MEM_;
  hist[((size_t)n*MEM_ + slot)*64 + b] = nv;
  float h[32];
  #pragma unroll
  for (int j = 0; j < 32; ++j) h[j] = b1[n*32+j];
  #pragma unroll 5
  for (int m = 0; m < MEM_; ++m) {
    int phys = (t + 1 + m) % MEM_;
    float hv = (m == MEM_-1) ? nv : hist[((size_t)n*MEM_ + phys)*64 + b];
    const float* wp = &W1[((size_t)n*MEM_ + m)*32];
    #pragma unroll
    for (int j = 0; j < 32; ++j) h[j] += hv * wp[j];
  }
  float acc = b2[n];
  #pragma unroll
  for (int j = 0; j < 32; ++j) acc += fmaxf(h[j], 0.f) * W2[n*32+j];
  actT[n*64 + b] = acc;
  preb[(size_t)b*1536 + 512 + n] = f2b(acc);
}

// ---------------------------------------------------------------------------
// Stage kernels: blocks 0-127 run the tick stage; blocks >=128 run piggy.
// ---------------------------------------------------------------------------
#define PIGGY_ARGS int pop, int poff, \
    const float* __restrict__ xg, int t0n, short* __restrict__ xTg, \
    const short* __restrict__ WkvT, \
    const float* __restrict__ bkv, short* __restrict__ kvpN, \
    float* __restrict__ muN, float* __restrict__ ivN, \
    const short* __restrict__ WkkvT, const float* __restrict__ gw, \
    const float* __restrict__ bw, short* __restrict__ KVTN, int McN
#define PIGGY_CALL run_piggy(tid, (int)blockIdx.x - 128, pop, poff, pool, \
    xg, t0n, xTg, WkvT, bkv, kvpN, muN, ivN, WkkvT, gw, bw, KVTN, McN)

__global__ __launch_bounds__(512) void stageA(
    const float* __restrict__ actT,
    float* __restrict__ aa, float* __restrict__ ba,
    const int* __restrict__ li_a, const int* __restrict__ ri_a,
    const float* __restrict__ decay_a,
    const short* __restrict__ WqqB, const float* __restrict__ bqh,
    const short* __restrict__ KVT, int ldkv, int ti,
    short* __restrict__ preb,
    float* __restrict__ ao, float* __restrict__ bo_s,
    const int* __restrict__ li_o, const int* __restrict__ ri_o,
    const float* __restrict__ decay_o,
    const short* __restrict__ WoutB, const float* __restrict__ bout,
    float* __restrict__ out, int t, PIGGY_ARGS)
{
  __shared__ __attribute__((aligned(16))) char pool[49152];
  const int bid = blockIdx.x, tid = threadIdx.x;
  if (bid < 128) {
    float* smem = (float*)pool;
    if (bid < 64)
      attn_body(bid, tid, smem, actT, aa, ba, li_a, ri_a, decay_a,
                WqqB, bqh, KVT, ldkv, ti, preb);
    else if (t > 0)
      outk_body(t-1, bid-64, tid, smem, smem+512, actT, ao, bo_s,
                li_o, ri_o, decay_o, WoutB, bout, out);
  } else {
    PIGGY_CALL;
  }
}

__global__ __launch_bounds__(512) void stageB(
    const short* __restrict__ preb, const short* __restrict__ WsynP,
    const float* __restrict__ bsynF, float* __restrict__ u, PIGGY_ARGS)
{
  __shared__ __attribute__((aligned(16))) char pool[49152];
  const int bid = blockIdx.x, tid = threadIdx.x;
  if (bid < 128) synglu_body(bid, tid, pool, preb, WsynP, bsynF, u);
  else PIGGY_CALL;
}

__global__ __launch_bounds__(512) void stageC(
    const float* __restrict__ u, const float* __restrict__ gsyn,
    const float* __restrict__ bln, float* __restrict__ hist,
    const float* __restrict__ W1, const float* __restrict__ b1,
    const float* __restrict__ W2, const float* __restrict__ b2,
    float* __restrict__ actT, short* __restrict__ preb, int t, PIGGY_ARGS)
{
  __shared__ __attribute__((aligned(16))) char pool[49152];
  const int bid = blockIdx.x, tid = threadIdx.x;
  if (bid < 128) nlmln_body(bid, tid, pool, u, gsyn, bln, hist,
                            W1, b1, W2, b2, actT, preb, t);
  else PIGGY_CALL;
}

// Final outk for t = T-1.
__global__ __launch_bounds__(512) void outk_fin(
    const float* __restrict__ actT,
    float* __restrict__ ao, float* __restrict__ bo_s,
    const int* __restrict__ li_o, const int* __restrict__ ri_o,
    const float* __restrict__ decay_o,
    const short* __restrict__ WoutB, const float* __restrict__ bout,
    float* __restrict__ out)
{
  __shared__ __attribute__((aligned(16))) float smem[544];
  outk_body(T_-1, blockIdx.x, threadIdx.x, smem, smem+512, actT, ao, bo_s,
            li_o, ri_o, decay_o, WoutB, bout, out);
}

// ---------------------------------------------------------------------------
// Standalone transpose of x over [t0, t0+tc): f32 [B][T][DF][S] -> bf16 rows
// ((t*B+b)*S + s) x [DF]  (global-t row indexing).
// ---------------------------------------------------------------------------
__global__ __launch_bounds__(256) void xpose_x(const float* __restrict__ x,
                                               short* __restrict__ xT, int t0, int tc)
{
  __shared__ float tile[32][33];
  int df0 = blockIdx.x*32, s0 = blockIdx.y*32;
  int z = blockIdx.z;
  int b = z / tc, ti = z % tc;
  int tx = threadIdx.x & 31, ty = threadIdx.x >> 5;
  const float* src = x + (size_t)(b*T_ + t0 + ti) * DF_ * S_;
  #pragma unroll
  for (int i = 0; i < 4; ++i) {
    int df = df0 + ty + i*8;
    int s  = s0 + tx;
    tile[ty+i*8][tx] = (s < S_) ? src[(size_t)df*S_ + s] : 0.f;
  }
  __syncthreads();
  short* dst = xT + (size_t)((t0 + ti)*B_ + b) * S_ * DIN_;
  #pragma unroll
  for (int i = 0; i < 4; ++i) {
    int s  = s0 + ty + i*8;
    int df = df0 + tx;
    if (s < S_) dst[(size_t)s*DF_ + df] = f2b(tile[tx][ty+i*8]);
  }
}

// Weight transpose f32->bf16, optional per-row scale.
__global__ __launch_bounds__(256) void wtrans(const float* __restrict__ in,
    short* __restrict__ out, int R, int C, int ldo, int coff,
    const float* __restrict__ scale)
{
  __shared__ float tile[32][33];
  int c0 = blockIdx.x*32, r0 = blockIdx.y*32;
  int tx = threadIdx.x & 31, ty = threadIdx.x >> 5;
  #pragma unroll
  for (int i = 0; i < 4; ++i) {
    int r = r0+ty+i*8;
    float sc = scale ? scale[r] : 1.f;
    tile[ty+i*8][tx] = in[(size_t)r*C + c0+tx] * sc;
  }
  __syncthreads();
  #pragma unroll
  for (int i = 0; i < 4; ++i)
    out[(size_t)(c0+ty+i*8)*ldo + coff + r0+tx] = f2b(tile[tx][ty+i*8]);
}

__global__ __launch_bounds__(256) void cvtb(const float* __restrict__ in,
                                            short* __restrict__ out, int n)
{
  int i = blockIdx.x*256 + threadIdx.x;
  if (i < n) out[i] = f2b(in[i]);
}

__global__ __launch_bounds__(256) void bias_fold(const float* __restrict__ vec,
    const float* __restrict__ W, const float* __restrict__ base,
    float* __restrict__ out, int N, int ldw)
{
  int n = blockIdx.x*256 + threadIdx.x;
  if (n >= N) return;
  float a = base ? base[n] : 0.f;
  #pragma unroll 8
  for (int k = 0; k < 512; ++k) a += vec[k]*W[(size_t)k*ldw + n];
  out[n] = a;
}

__global__ __launch_bounds__(256) void permrows(const short* __restrict__ in,
                                                short* __restrict__ out)
{
  int r = blockIdx.x;
  int k = r >> 4, i = r & 15;
  int src = (i < 8) ? (k*8 + i) : (1024 + k*8 + (i - 8));
  const bf16x8* s = (const bf16x8*)(in + (size_t)src*1536);
  bf16x8* d = (bf16x8*)(out + (size_t)r*1536);
  int j = threadIdx.x;
  if (j < 192) d[j] = s[j];
}

// Standalone per-row LN stats (chunk 0 / fallback).
__global__ __launch_bounds__(256) void ln_stats(const short* __restrict__ in,
    float* __restrict__ mu, float* __restrict__ iv, int nrows)
{
  int w = threadIdx.x >> 6, l = threadIdx.x & 63;
  int r = blockIdx.x*4 + w;
  if (r >= nrows) return;
  bf16x8 v8 = *(const bf16x8*)&in[(size_t)r*512 + l*8];
  float s = 0.f, s2 = 0.f;
  #pragma unroll
  for (int j = 0; j < 8; ++j) { float v = b2f(v8[j]); s += v; s2 += v*v; }
  #pragma unroll
  for (int m = 1; m < 64; m <<= 1) { s += __shfl_xor(s, m, 64); s2 += __shfl_xor(s2, m, 64); }
  if (l == 0) {
    float mean = s * (1.f/512.f);
    float var  = s2 * (1.f/512.f) - mean*mean;
    mu[r] = mean;
    iv[r] = rsqrtf(var + 1e-5f);
  }
}

// Re-initialize all recurrent state (graph-replay deterministic).
__global__ __launch_bounds__(256) void initk(float* __restrict__ aa, float* __restrict__ ba,
    float* __restrict__ ao, float* __restrict__ bo_s,
    float* __restrict__ actT, float* __restrict__ hist, short* __restrict__ preb,
    const float* __restrict__ init_act, const float* __restrict__ init_hist,
    const int* __restrict__ li_o, const int* __restrict__ ri_o)
{
  int i = blockIdx.x*256 + threadIdx.x;
  if (i < 64*512) {
    aa[i] = 0.f; ba[i] = 0.f;
    int j = i & 511;
    ao[i] = init_act[li_o[j]] * init_act[ri_o[j]];
    bo_s[i] = 1.f;
  }
  if (i < 65536) {
    int n = i >> 6, b = i & 63;
    actT[i] = init_act[n];
    preb[(size_t)b*1536 + 512 + n] = f2b(init_act[n]);
  }
  if (i < DM_*MEM_*64) {
    int nm = i >> 6;
    hist[i] = init_hist[nm];
  }
}

// ---------------------------------------------------------------------------
extern "C" void kernel_launch(void* const* d_in, const int* in_sizes, int n_in,
                              void* d_out, int out_size, void* d_ws, size_t ws_size,
                              hipStream_t stream)
{
  (void)in_sizes; (void)n_in; (void)out_size;
  const float* x       = (const float*)d_in[0];
  const float* Wqp     = (const float*)d_in[1];
  const float* bqp     = (const float*)d_in[2];
  const float* Wkv     = (const float*)d_in[3];
  const float* bkv     = (const float*)d_in[4];
  const float* g_kv    = (const float*)d_in[5];
  const float* b_kv    = (const float*)d_in[6];
  const float* Wq      = (const float*)d_in[7];
  const float* bq      = (const float*)d_in[8];
  const float* Wk      = (const float*)d_in[9];
  const float* bk      = (const float*)d_in[10];
  const float* Wv      = (const float*)d_in[11];
  const float* bv      = (const float*)d_in[12];
  const float* Wo      = (const float*)d_in[13];
  const float* bo_p    = (const float*)d_in[14];
  const float* Wsyn    = (const float*)d_in[15];
  const float* bsyn    = (const float*)d_in[16];
  const float* g_syn   = (const float*)d_in[17];
  const float* b_syn   = (const float*)d_in[18];
  const float* W1      = (const float*)d_in[19];
  const float* b1      = (const float*)d_in[20];
  const float* W2      = (const float*)d_in[21];
  const float* b2      = (const float*)d_in[22];
  const float* init_act  = (const float*)d_in[23];
  const float* init_hist = (const float*)d_in[24];
  const float* decay_a = (const float*)d_in[25];
  const float* decay_o = (const float*)d_in[26];
  const float* Wout    = (const float*)d_in[27];
  const float* bout    = (const float*)d_in[28];
  const int* li_a = (const int*)d_in[29];
  const int* ri_a = (const int*)d_in[30];
  const int* li_o = (const int*)d_in[31];
  const int* ri_o = (const int*)d_in[32];

  char* ws = (char*)d_ws;
  size_t off = 0;
  auto alloc = [&](size_t bytes) { char* p = ws + off; off += (bytes + 255) & ~(size_t)255; return p; };
  short* WkvT   = (short*)alloc(512*512*2);
  short* WkkvT  = (short*)alloc(1024*512*2);
  short* WsynF  = (short*)alloc(2048*1536*2);
  short* WsynP  = (short*)alloc(2048*1536*2);
  short* WsynTt = (short*)alloc(2048*512*2);
  short* WqpB   = (short*)alloc(512*512*2);
  short* WqT    = (short*)alloc(512*512*2);
  short* WoB    = (short*)alloc(512*512*2);
  short* WqqB   = (short*)alloc(512*512*2);
  short* WoutB  = (short*)alloc(512*512*2);
  float* bqh    = (float*)alloc(512*4);
  float* bsynF  = (float*)alloc(2048*4);
  float* gw     = (float*)alloc(1024*4);
  float* bw     = (float*)alloc(1024*4);
  short* preb   = (short*)alloc(64*1536*2);
  float* u      = (float*)alloc(64*1024*4);
  float* aa     = (float*)alloc(64*512*4);
  float* ba     = (float*)alloc(64*512*4);
  float* ao     = (float*)alloc(64*512*4);
  float* bo_s   = (float*)alloc(64*512*4);
  float* actT   = (float*)alloc(1024*64*4);
  float* hist   = (float*)alloc((size_t)1024*25*64*4);
  size_t fixed_end = off;

  const size_t szXT  = (size_t)T_*MR_*512*2;     // 205.5 MB (all 16 ticks)
  const size_t szKVP = (size_t)MCC_*512*2;       //  51.4 MB per chunk
  const size_t szKVT = (size_t)MCC_*1024*2;      // 102.8 MB per chunk
  const size_t szST  = (size_t)MCC_*4;           //   0.2 MB
  size_t need_full = fixed_end + szXT + 2*szKVP + 2*szKVT + 4*szST + 4096;
  bool pig_en = (ws_size >= need_full);

  short* xT = (short*)alloc(szXT);
  short* kvpB[2]; short* KVTB[2]; float* muB[2]; float* ivB[2];
  kvpB[0] = (short*)alloc(szKVP);
  KVTB[0] = (short*)alloc(szKVT);
  muB[0]  = (float*)alloc(szST);
  ivB[0]  = (float*)alloc(szST);
  if (pig_en) {
    kvpB[1] = (short*)alloc(szKVP);
    KVTB[1] = (short*)alloc(szKVT);
    muB[1]  = (float*)alloc(szST);
    ivB[1]  = (float*)alloc(szST);
  } else {
    kvpB[1] = kvpB[0]; KVTB[1] = KVTB[0]; muB[1] = muB[0]; ivB[1] = ivB[0];
  }

  const int BIG = 1 << 30;
  const float* FN = nullptr;

  initk<<<6400, 256, 0, stream>>>(aa, ba, ao, bo_s, actT, hist, preb,
                                  init_act, init_hist, li_o, ri_o);
  wtrans<<<dim3(16,16), 256, 0, stream>>>(Wkv, WkvT, 512, 512, 512, 0, nullptr);
  wtrans<<<dim3(16,16), 256, 0, stream>>>(Wk,  WkkvT, 512, 512, 512, 0, g_kv);
  wtrans<<<dim3(16,16), 256, 0, stream>>>(Wv,  WkkvT + (size_t)512*512, 512, 512, 512, 0, g_kv);
  wtrans<<<dim3(64,32), 256, 0, stream>>>(Wsyn + (size_t)512*2048, WsynF, 1024, 2048, 1536, 512, nullptr);
  wtrans<<<dim3(64,16), 256, 0, stream>>>(Wsyn, WsynTt, 512, 2048, 512, 0, nullptr);
  wtrans<<<dim3(16,16), 256, 0, stream>>>(Wq,  WqT, 512, 512, 512, 0, nullptr);
  cvtb<<<1024, 256, 0, stream>>>(Wqp, WqpB, 512*512);
  cvtb<<<1024, 256, 0, stream>>>(Wo,  WoB,  512*512);
  cvtb<<<1024, 256, 0, stream>>>(Wout, WoutB, 512*512);
  gemm_k<0,0><<<dim3(4,4), 256, 0, stream>>>(WqpB, WqT, WqqB, nullptr, nullptr, BIG,
                                             FN, FN, FN, FN, 512, 512, 512, 512, 512);
  gemm_k<0,0><<<dim3(16,4), 256, 0, stream>>>(WsynTt, WoB, WsynF, nullptr, nullptr, BIG,
                                              FN, FN, FN, FN, 2048, 512, 512, 512, 1536);
  permrows<<<2048, 256, 0, stream>>>(WsynF, WsynP);
  bias_fold<<<2, 256, 0, stream>>>(bqp,  Wq,   bq,   bqh,   512,  512);
  bias_fold<<<8, 256, 0, stream>>>(bo_p, Wsyn, bsyn, bsynF, 2048, 2048);
  bias_fold<<<2, 256, 0, stream>>>(g_kv, Wk, nullptr, gw,       512, 512);
  bias_fold<<<2, 256, 0, stream>>>(g_kv, Wv, nullptr, gw + 512, 512, 512);
  bias_fold<<<2, 256, 0, stream>>>(b_kv, Wk, bk, bw,       512, 512);
  bias_fold<<<2, 256, 0, stream>>>(b_kv, Wv, bv, bw + 512, 512, 512);

  // upfront transpose: chunk 0 only when piggybacking, all 16 ticks otherwise
  if (pig_en)
    xpose_x<<<dim3(16,7,B_*TC_), 256, 0, stream>>>(x, xT, 0, TC_);
  else
    xpose_x<<<dim3(16,7,B_*T_), 256, 0, stream>>>(x, xT, 0, T_);

  auto run_pipe = [&](int c, short* kvpP, float* muP, float* ivP, short* KVTP){
    const short* xTc = xT + (size_t)c*TC_*MR_*512;
    gemm_k<0,0><<<dim3(392,4), 256, 0, stream>>>(xTc, WkvT, kvpP, bkv, bkv, BIG,
                                                 FN, FN, FN, FN, MCC_, 512, 512, 512, 512);
    ln_stats<<<MCC_/4, 256, 0, stream>>>(kvpP, muP, ivP, MCC_);
    gemm_k<0,2><<<dim3(8,392), 256, 0, stream>>>(WkkvT, kvpP, KVTP, nullptr, nullptr, BIG,
                                                 muP, ivP, gw, bw, 1024, MCC_, 512, 512, MCC_);
  };

  // per-chunk piggy schedule over the 12 tail launches:
  // q 0-1: op4 xpose (448 blk); q 2-5: op1 kv-GEMM (196 twin-pairs);
  // q 6: op2 stats (784 blk); q 7-11: op3 KVT (314 twin-pairs, clamped).
  auto pigcfg = [](int q, bool pig, int& op, int& pf, int& n){
    op = 0; pf = 0; n = 0;
    if (!pig) return;
    if (q < 2)      { op = 4; pf = q*448;     n = 448; }
    else if (q < 6) { op = 1; pf = (q-2)*196; n = 196; }
    else if (q == 6){ op = 2; pf = 0;         n = 784; }
    else            { op = 3; pf = (q-7)*314; n = 314; }
  };

  run_pipe(0, kvpB[0], muB[0], ivB[0], KVTB[0]);

  for (int c = 0; c < 4; ++c) {
    int par = pig_en ? (c & 1) : 0;
    int nxt = pig_en ? (par ^ 1) : 0;
    if (!pig_en && c > 0) run_pipe(c, kvpB[0], muB[0], ivB[0], KVTB[0]);
    bool pig = pig_en && (c < 3);
    int t0n = (c < 3) ? (c+1)*TC_ : 0;
    for (int ti = 0; ti < TC_; ++ti) {
      int t = c*TC_ + ti;
      int op, pf, n;
      pigcfg(ti*3+0, pig, op, pf, n);
      stageA<<<128+n, 512, 0, stream>>>(actT, aa, ba, li_a, ri_a, decay_a,
          WqqB, bqh, KVTB[par], MCC_, ti, preb,
          ao, bo_s, li_o, ri_o, decay_o, WoutB, bout, (float*)d_out, t,
          op, pf, x, t0n, xT, WkvT, bkv, kvpB[nxt], muB[nxt], ivB[nxt],
          WkkvT, gw, bw, KVTB[nxt], MCC_);
      pigcfg(ti*3+1, pig, op, pf, n);
      stageB<<<128+n, 512, 0, stream>>>(preb, WsynP, bsynF, u,
          op, pf, x, t0n, xT, WkvT, bkv, kvpB[nxt], muB[nxt], ivB[nxt],
          WkkvT, gw, bw, KVTB[nxt], MCC_);
      pigcfg(ti*3+2, pig, op, pf, n);
      stageC<<<128+n, 512, 0, stream>>>(u, g_syn, b_syn, hist,
          W1, b1, W2, b2, actT, preb, t,
          op, pf, x, t0n, xT, WkvT, bkv, kvpB[nxt], muB[nxt], ivB[nxt],
          WkkvT, gw, bw, KVTB[nxt], MCC_);
    }
  }
  outk_fin<<<64, 512, 0, stream>>>(actT, ao, bo_s, li_o, ri_o, decay_o,
                                   WoutB, bout, (float*)d_out);
}

// Round 12
// 2026.684 us; speedup vs baseline: 2.3677x; 1.1575x over previous
//
#include <hip/hip_runtime.h>
#include <stdint.h>
#include <stddef.h>

#define B_    64
#define T_    16
#define DF_   512
#define S_    196
#define DIN_  512
#define H_    8
#define DH_   64
#define DM_   1024
#define MEM_  25
#define HN_   32
#define MR_   (B_*S_)     /* 12544 rows per tick */
#define TC_   2           /* ticks per chunk */
#define NCH_  (T_/TC_)    /* 8 chunks */
#define MCC_  (MR_*TC_)   /* 25088 rows per chunk */

typedef short bf16x8 __attribute__((ext_vector_type(8)));
typedef short short4v __attribute__((ext_vector_type(4)));
typedef float f32x4  __attribute__((ext_vector_type(4)));

__device__ __forceinline__ float b2f(short h){
  unsigned u = ((unsigned)(unsigned short)h) << 16;
  float f; __builtin_memcpy(&f, &u, 4); return f;
}
__device__ __forceinline__ short f2b(float f){
  unsigned u; __builtin_memcpy(&u, &f, 4);
  u = (u + 0x7fffu + ((u >> 16) & 1u)) >> 16;
  return (short)(unsigned short)u;
}
__device__ __forceinline__ float clip015(float d){
  return d < 0.f ? 0.f : (d > 15.f ? 15.f : d);
}

// ---------------------------------------------------------------------------
// bf16 MFMA GEMM body (verified R8/R11 code). 128x128 tile, BK=64, 4 waves
// 2x2 over tid 0..255, 16x16x32 MFMA, global_load_lds width-16, XOR chunk
// swizzle. aload=0 lets a twin block skip A-tile loads (shared lA).
// LNEPI=0: +bias. LNEPI=2: transposed-LN fold (col stats, row gw/bw).
// No spins / unbounded waits anywhere in this file: every kernel terminates.
// ---------------------------------------------------------------------------
template<int OUTF32, int LNEPI>
__device__ __forceinline__ void gemm_body(int tid, int bx, int by, int aload,
    short* lA, short* lB,
    const short* __restrict__ A, const short* __restrict__ WT,
    void* __restrict__ Cout,
    const float* __restrict__ biasA, const float* __restrict__ biasB, int nsplit,
    const float* __restrict__ mu, const float* __restrict__ iv,
    const float* __restrict__ gw, const float* __restrict__ bw,
    int M, int N, int K, int lda, int ldc)
{
  const int w = tid >> 6, l = tid & 63;
  const int m0 = bx * 128, n0 = by * 128;
  const int wm = (w >> 1) * 64, wn = (w & 1) * 64;
  f32x4 acc[4][4];
  #pragma unroll
  for (int i=0;i<4;i++)
    #pragma unroll
    for (int j=0;j<4;j++) acc[i][j] = (f32x4){0.f,0.f,0.f,0.f};

  for (int k0 = 0; k0 < K; k0 += 64) {
    #pragma unroll
    for (int rnd = 0; rnd < 4; ++rnd) {
      int cb = (rnd*4 + w) * 64;
      int slot = cb + l;
      int row = slot >> 3, kb = slot & 7;
      int kc = k0 + ((kb ^ (row & 7)) << 3);
      if (aload) {
        int gm = m0 + row; if (gm > M-1) gm = M-1;
        __builtin_amdgcn_global_load_lds(
            (const __attribute__((address_space(1))) void*)(A + (size_t)gm * lda + kc),
            (__attribute__((address_space(3))) void*)&lA[cb*8], 16, 0, 0);
      }
      __builtin_amdgcn_global_load_lds(
          (const __attribute__((address_space(1))) void*)(WT + (size_t)(n0 + row) * K + kc),
          (__attribute__((address_space(3))) void*)&lB[cb*8], 16, 0, 0);
    }
    asm volatile("s_waitcnt vmcnt(0)" ::: "memory");
    __syncthreads();
    #pragma unroll
    for (int ks = 0; ks < 2; ++ks) {
      bf16x8 af[4], bfr[4];
      #pragma unroll
      for (int i = 0; i < 4; ++i) {
        int ra = wm + i*16 + (l & 15);
        int c  = ks*4 + (l >> 4);
        af[i]  = *(const bf16x8*)&lA[ra*64 + ((c ^ (ra & 7)) << 3)];
        int rb = wn + i*16 + (l & 15);
        bfr[i] = *(const bf16x8*)&lB[rb*64 + ((c ^ (rb & 7)) << 3)];
      }
      #pragma unroll
      for (int i = 0; i < 4; ++i)
        #pragma unroll
        for (int j = 0; j < 4; ++j)
          acc[i][j] = __builtin_amdgcn_mfma_f32_16x16x32_bf16(af[i], bfr[j], acc[i][j], 0, 0, 0);
    }
    __syncthreads();
  }
  #pragma unroll
  for (int i = 0; i < 4; ++i) {
    #pragma unroll
    for (int j = 0; j < 4; ++j) {
      int gn = n0 + wn + j*16 + (l & 15);
      float ivn = 0.f, mun = 0.f, bb = 0.f;
      if (LNEPI == 2) { ivn = iv[gn]; mun = mu[gn]; }
      else bb = biasA ? ((gn < nsplit) ? biasA[gn] : biasB[gn - nsplit]) : 0.f;
      #pragma unroll
      for (int r = 0; r < 4; ++r) {
        int gm = m0 + wm + i*16 + (l >> 4)*4 + r;
        if (gm < M) {
          float v;
          if (LNEPI == 2) v = ivn*(acc[i][j][r] - mun*gw[gm]) + bw[gm];
          else            v = acc[i][j][r] + bb;
          if (OUTF32) ((float*)Cout)[(size_t)gm * ldc + gn] = v;
          else        ((short*)Cout)[(size_t)gm * ldc + gn] = f2b(v);
        }
      }
    }
  }
}

// Standalone 256-thread GEMM kernel (chunk-0 pipeline / fallback).
template<int OUTF32, int LNEPI>
__global__ __launch_bounds__(256,2) void gemm_k(
    const short* __restrict__ A, const short* __restrict__ WT,
    void* __restrict__ Cout,
    const float* __restrict__ biasA, const float* __restrict__ biasB, int nsplit,
    const float* __restrict__ mu, const float* __restrict__ iv,
    const float* __restrict__ gw, const float* __restrict__ bw,
    int M, int N, int K, int lda, int ldc)
{
  __shared__ short lA[128*64];
  __shared__ short lB[128*64];
  gemm_body<OUTF32,LNEPI>(threadIdx.x, blockIdx.x, blockIdx.y, 1, lA, lB,
                          A, WT, Cout, biasA, biasB, nsplit, mu, iv, gw, bw,
                          M, N, K, lda, ldc);
}

// Both weight-fold GEMMs in one launch (independent; inputs from prep_all).
__global__ __launch_bounds__(256,2) void gemm_prep2(
    const short* __restrict__ WqpB, const short* __restrict__ WqT,
    short* __restrict__ WqqB,
    const short* __restrict__ WsynTt, const short* __restrict__ WoB,
    short* __restrict__ WsynF)
{
  __shared__ short lA[128*64];
  __shared__ short lB[128*64];
  int blk = blockIdx.x;
  if (blk < 16)
    gemm_body<0,0>(threadIdx.x, blk & 3, blk >> 2, 1, lA, lB, WqpB, WqT, WqqB,
                   nullptr, nullptr, 1<<30, nullptr, nullptr, nullptr, nullptr,
                   512, 512, 512, 512, 512);
  else {
    int b2 = blk - 16;
    gemm_body<0,0>(threadIdx.x, b2 & 15, b2 >> 4, 1, lA, lB, WsynTt, WoB, WsynF,
                   nullptr, nullptr, 1<<30, nullptr, nullptr, nullptr, nullptr,
                   2048, 512, 512, 512, 1536);
  }
}

// ---------------------------------------------------------------------------
// Piggyback dispatcher (TC_=2 chunk geometry).
// op4 = x-transpose slice: 448 blocks x 32 tiles = 14336 = 16df x 7s x 128(b,ti)
// op1 = kv-GEMM twin-pair: 392 pairs = 196bx x 2byp (784 tiles)
// op2 = ln_stats: 392 blocks x 64 rows = 25088
// op3 = KVT-GEMM twin-pair: 784 pairs = 8bx x 98byp (1568 tiles)
// ---------------------------------------------------------------------------
__device__ __forceinline__ void run_piggy(int tid, int pb, int pop, int poff,
    char* pool,
    const float* __restrict__ xg, int t0n, short* __restrict__ xT,
    const short* __restrict__ WkvT, const float* __restrict__ bkv,
    short* __restrict__ kvpN, float* __restrict__ muN, float* __restrict__ ivN,
    const short* __restrict__ WkkvT, const float* __restrict__ gw,
    const float* __restrict__ bw, short* __restrict__ KVTN, int McN)
{
  if (pop == 4) {
    int twin = tid >> 8, tid2 = tid & 255;
    float* tile = (float*)(pool + twin*8448);   // [32][33] f32
    int tx = tid2 & 31, ty = tid2 >> 5;
    int base = (poff + pb)*32 + twin*16;
    for (int it = 0; it < 16; ++it) {
      int gt = base + it;
      int df0 = (gt & 15) * 32;
      int r = gt >> 4;
      int s0 = (r % 7) * 32;
      int z = r / 7;              // [0,128)
      int b = z >> 1, ti = z & 1;
      const float* src = xg + (size_t)(b*T_ + t0n + ti) * DF_ * S_;
      #pragma unroll
      for (int i = 0; i < 4; ++i) {
        int df = df0 + ty + i*8;
        int s  = s0 + tx;
        tile[(ty+i*8)*33 + tx] = (s < S_) ? src[(size_t)df*S_ + s] : 0.f;
      }
      __syncthreads();
      short* dst = xT + (size_t)((t0n + ti)*B_ + b) * S_ * DIN_;
      #pragma unroll
      for (int i = 0; i < 4; ++i) {
        int s  = s0 + ty + i*8;
        int df = df0 + tx;
        if (s < S_) dst[(size_t)s*DF_ + df] = f2b(tile[tx*33 + ty+i*8]);
      }
      __syncthreads();
    }
  } else if (pop == 1) {
    int twin = tid >> 8;
    short* lA = (short*)pool;
    short* lB = (short*)(pool + 16384 + 16384*twin);
    int p = poff + pb; if (p > 391) p = 391;
    int bx = p % 196, byp = p / 196;
    const short* xTn = xT + (size_t)t0n * MR_ * 512;
    gemm_body<0,0>(tid & 255, bx, byp*2 + twin, twin == 0, lA, lB,
                   xTn, WkvT, kvpN, bkv, bkv, 1 << 30,
                   nullptr, nullptr, nullptr, nullptr,
                   McN, 512, 512, 512, 512);
  } else if (pop == 2) {
    int blk = poff + pb;
    int w = tid >> 6, l = tid & 63;
    for (int i = 0; i < 8; ++i) {
      int r = blk*64 + i*8 + w;
      if (r < McN) {
        bf16x8 v8 = *(const bf16x8*)&kvpN[(size_t)r*512 + l*8];
        float s = 0.f, s2 = 0.f;
        #pragma unroll
        for (int j = 0; j < 8; ++j) { float v = b2f(v8[j]); s += v; s2 += v*v; }
        #pragma unroll
        for (int m = 1; m < 64; m <<= 1) { s += __shfl_xor(s, m, 64); s2 += __shfl_xor(s2, m, 64); }
        if (l == 0) {
          float mean = s * (1.f/512.f);
          float var  = s2 * (1.f/512.f) - mean*mean;
          muN[r] = mean;
          ivN[r] = rsqrtf(var + 1e-5f);
        }
      }
    }
  } else if (pop == 3) {
    int twin = tid >> 8;
    short* lA = (short*)pool;
    short* lB = (short*)(pool + 16384 + 16384*twin);
    int p = poff + pb; if (p > 783) p = 783;
    int bx = p % 8, byp = p / 8;
    gemm_body<0,2>(tid & 255, bx, byp*2 + twin, twin == 0, lA, lB,
                   WkkvT, kvpN, KVTN, nullptr, nullptr, 0,
                   muN, ivN, gw, bw, 1024, McN, 512, 512, McN);
  }
}

// ---------------------------------------------------------------------------
// Tick bodies (verified R8/R11 logic, pool-based LDS).
// ---------------------------------------------------------------------------
__device__ __forceinline__ void attn_body(int b, int tid, float* smem,
    const float* actT, float* aa, float* ba,
    const int* li_a, const int* ri_a, const float* decay_a,
    const short* WqqB, const float* bqh,
    const short* KVT, int ldkv, int ti, short* preb)
{
  float* syncL = smem;
  float* qhL   = smem + 512;
  float* pL    = smem + 1024;   // 8*256
  int j = tid;
  float rr = expf(-clip015(decay_a[j]));
  float prod = actT[li_a[j]*64 + b] * actT[ri_a[j]*64 + b];
  float a2 = rr*aa[b*512+j] + prod; aa[b*512+j] = a2;
  float bb2 = rr*ba[b*512+j] + 1.f;  ba[b*512+j] = bb2;
  syncL[j] = a2 * rsqrtf(bb2);
  __syncthreads();
  float qa = bqh[j];
  #pragma unroll 8
  for (int k = 0; k < 512; ++k) qa += syncL[k]*b2f(WqqB[k*512+j]);
  qhL[j] = qa;
  __syncthreads();
  int h = tid >> 6, l = tid & 63;
  const size_t cb = (size_t)(ti*B_ + b) * S_;
  const short* Kb = KVT + (size_t)(h*64)*ldkv + cb;
  int s3 = 192 + l; int s3c = s3 < S_ ? s3 : S_-1;
  float sc0=0.f, sc1=0.f, sc2=0.f, sc3=0.f;
  #pragma unroll 8
  for (int d = 0; d < 64; ++d) {
    const short* kr = Kb + (size_t)d*ldkv;
    float qv = qhL[h*64 + d];
    sc0 += qv * b2f(kr[l]);
    sc1 += qv * b2f(kr[64 + l]);
    sc2 += qv * b2f(kr[128 + l]);
    sc3 += qv * b2f(kr[s3c]);
  }
  sc0 *= 0.125f; sc1 *= 0.125f; sc2 *= 0.125f;
  sc3 = (s3 < S_) ? sc3*0.125f : -1e30f;
  float mx = fmaxf(fmaxf(sc0, sc1), fmaxf(sc2, sc3));
  #pragma unroll
  for (int k = 32; k >= 1; k >>= 1) mx = fmaxf(mx, __shfl_xor(mx, k, 64));
  float p0 = expf(sc0-mx), p1 = expf(sc1-mx), p2 = expf(sc2-mx), p3 = expf(sc3-mx);
  pL[h*256 + l] = p0; pL[h*256 + 64+l] = p1;
  pL[h*256 + 128+l] = p2; pL[h*256 + 192+l] = p3;
  float ps = p0+p1+p2+p3;
  #pragma unroll
  for (int k = 32; k >= 1; k >>= 1) ps += __shfl_xor(ps, k, 64);
  float inv = 1.f / ps;
  __syncthreads();
  const short4v* vrow = (const short4v*)(KVT + (size_t)(512 + h*64 + l)*ldkv + cb);
  const float* pp = pL + h*256;
  float ac0=0.f, ac1=0.f, ac2=0.f, ac3=0.f;
  #pragma unroll 7
  for (int c = 0; c < 49; ++c) {
    short4v v4 = vrow[c];
    ac0 += pp[c*4]   * b2f(v4.x);
    ac1 += pp[c*4+1] * b2f(v4.y);
    ac2 += pp[c*4+2] * b2f(v4.z);
    ac3 += pp[c*4+3] * b2f(v4.w);
  }
  float accv = (ac0+ac1)+(ac2+ac3);
  preb[(size_t)b*1536 + h*64 + l] = f2b(accv * inv);
}

__device__ __forceinline__ void outk_body(int tt, int b, int tid,
    float* syncL, float* wred,
    const float* actT, float* ao, float* bo_s,
    const int* li_o, const int* ri_o, const float* decay_o,
    const short* WoutB, const float* bout, float* out)
{
  int j = tid;
  float rr = expf(-clip015(decay_o[j]));
  float prod = actT[li_o[j]*64 + b] * actT[ri_o[j]*64 + b];
  float a2 = rr*ao[b*512+j] + prod; ao[b*512+j] = a2;
  float bb2 = rr*bo_s[b*512+j] + 1.f; bo_s[b*512+j] = bb2;
  syncL[j] = a2 * rsqrtf(bb2);
  __syncthreads();
  float a = bout[j];
  #pragma unroll 8
  for (int k = 0; k < 512; ++k) a += syncL[k]*b2f(WoutB[k*512+j]);
  out[((size_t)b*512 + j)*16 + tt] = a;
  int w = tid >> 6, l = tid & 63;
  float m = a;
  #pragma unroll
  for (int k = 32; k >= 1; k >>= 1) m = fmaxf(m, __shfl_xor(m, k, 64));
  if (l == 0) wred[w] = m;
  __syncthreads();
  float M = wred[0];
  #pragma unroll
  for (int k = 1; k < 8; ++k) M = fmaxf(M, wred[k]);
  float e = expf(a - M);
  float z = e, s1 = e*(a - M);
  #pragma unroll
  for (int k = 32; k >= 1; k >>= 1) { z += __shfl_xor(z, k, 64); s1 += __shfl_xor(s1, k, 64); }
  if (l == 0) { wred[8+w] = z; wred[16+w] = s1; }
  __syncthreads();
  if (tid == 0) {
    float Z = 0.f, S1 = 0.f;
    #pragma unroll
    for (int k = 0; k < 8; ++k) { Z += wred[8+k]; S1 += wred[16+k]; }
    float plp = S1 / Z - logf(Z);
    float ne = -plp * (1.f/logf(512.f));
    out[524288 + (size_t)b*32 + tt]      = ne;
    out[524288 + (size_t)b*32 + 16 + tt] = 1.f - ne;
  }
}

__device__ __forceinline__ void synglu_body(int bid, int tid, char* pool,
    const short* preb, const short* WsynP, const float* bsynF, float* u)
{
  f32x4* part = (f32x4*)pool;
  int w = tid >> 6, l = tid & 63;
  int mf = w & 3, kh = w >> 2;
  int arow = mf*16 + (l & 15);
  int kbase = kh*768 + (l >> 4)*8;
  const short* ap = preb + (size_t)arow*1536 + kbase;
  const short* bp = WsynP + (size_t)(bid*16 + (l & 15))*1536 + kbase;
  f32x4 acc = (f32x4){0.f,0.f,0.f,0.f};
  #pragma unroll 4
  for (int ks = 0; ks < 24; ++ks) {
    bf16x8 av = *(const bf16x8*)(ap + ks*32);
    bf16x8 bv = *(const bf16x8*)(bp + ks*32);
    acc = __builtin_amdgcn_mfma_f32_16x16x32_bf16(av, bv, acc, 0, 0, 0);
  }
  part[w*64 + l] = acc;
  __syncthreads();
  if (w < 4) {
    f32x4 o1 = part[w*64 + l], o2 = part[(w+4)*64 + l];
    int c = l & 15;
    int colg = bid*8 + (c & 7);
    float bias = (c < 8) ? bsynF[colg] : bsynF[1024 + colg];
    float tv[4], pv[4];
    #pragma unroll
    for (int r2 = 0; r2 < 4; ++r2) tv[r2] = o1[r2] + o2[r2] + bias;
    #pragma unroll
    for (int r2 = 0; r2 < 4; ++r2) pv[r2] = __shfl_xor(tv[r2], 8, 64);
    if (c < 8) {
      #pragma unroll
      for (int r2 = 0; r2 < 4; ++r2) {
        float uu = tv[r2] * (1.f/(1.f + expf(-pv[r2])));
        int brow = w*16 + (l >> 4)*4 + r2;
        u[brow*1024 + colg] = uu;
      }
    }
  }
}

__device__ __forceinline__ void nlmln_body(int bid, int tid, char* pool,
    const float* u, const float* gsyn, const float* bln, float* hist,
    const float* W1, const float* b1, const float* W2, const float* b2,
    float* actT, short* preb, int t)
{
  float* mstat = (float*)pool;
  float* istat = mstat + 64;
  {
    int b = tid >> 3, p = tid & 7;
    const float* up = u + b*1024 + p*128;
    float s = 0.f, s2 = 0.f;
    #pragma unroll 8
    for (int i = 0; i < 128; ++i) { float v = up[i]; s += v; s2 += v*v; }
    #pragma unroll
    for (int k = 4; k >= 1; k >>= 1) { s += __shfl_xor(s, k, 64); s2 += __shfl_xor(s2, k, 64); }
    if (p == 0) {
      float mean = s * (1.f/1024.f);
      float var  = s2 * (1.f/1024.f) - mean*mean;
      mstat[b] = mean;
      istat[b] = rsqrtf(var + 1e-5f);
    }
  }
  __syncthreads();
  int n = (bid << 3) + (tid >> 6), b = tid & 63;
  float nv = (u[b*1024 + n] - mstat[b]) * istat[b] * gsyn[n] + bln[n];
  int slot = t % MEM_;
  hist[((size_t)n*MEM_ + slot)*64 + b] = nv;
  float h[32];
  #pragma unroll
  for (int j = 0; j < 32; ++j) h[j] = b1[n*32+j];
  #pragma unroll 5
  for (int m = 0; m < MEM_; ++m) {
    int phys = (t + 1 + m) % MEM_;
    float hv = (m == MEM_-1) ? nv : hist[((size_t)n*MEM_ + phys)*64 + b];
    const float* wp = &W1[((size_t)n*MEM_ + m)*32];
    #pragma unroll
    for (int j = 0; j < 32; ++j) h[j] += hv * wp[j];
  }
  float acc = b2[n];
  #pragma unroll
  for (int j = 0; j < 32; ++j) acc += fmaxf(h[j], 0.f) * W2[n*32+j];
  actT[n*64 + b] = acc;
  preb[(size_t)b*1536 + 512 + n] = f2b(acc);
}

// ---------------------------------------------------------------------------
// Stage kernels: blocks 0-127 run the tick stage; blocks >=128 run piggy.
// ---------------------------------------------------------------------------
#define PIGGY_ARGS int pop, int poff, \
    const float* __restrict__ xg, int t0n, short* __restrict__ xTg, \
    const short* __restrict__ WkvT, \
    const float* __restrict__ bkv, short* __restrict__ kvpN, \
    float* __restrict__ muN, float* __restrict__ ivN, \
    const short* __restrict__ WkkvT, const float* __restrict__ gw, \
    const float* __restrict__ bw, short* __restrict__ KVTN, int McN
#define PIGGY_CALL run_piggy(tid, (int)blockIdx.x - 128, pop, poff, pool, \
    xg, t0n, xTg, WkvT, bkv, kvpN, muN, ivN, WkkvT, gw, bw, KVTN, McN)

__global__ __launch_bounds__(512) void stageA(
    const float* __restrict__ actT,
    float* __restrict__ aa, float* __restrict__ ba,
    const int* __restrict__ li_a, const int* __restrict__ ri_a,
    const float* __restrict__ decay_a,
    const short* __restrict__ WqqB, const float* __restrict__ bqh,
    const short* __restrict__ KVT, int ldkv, int ti,
    short* __restrict__ preb,
    float* __restrict__ ao, float* __restrict__ bo_s,
    const int* __restrict__ li_o, const int* __restrict__ ri_o,
    const float* __restrict__ decay_o,
    const short* __restrict__ WoutB, const float* __restrict__ bout,
    float* __restrict__ out, int t, PIGGY_ARGS)
{
  __shared__ __attribute__((aligned(16))) char pool[49152];
  const int bid = blockIdx.x, tid = threadIdx.x;
  if (bid < 128) {
    float* smem = (float*)pool;
    if (bid < 64)
      attn_body(bid, tid, smem, actT, aa, ba, li_a, ri_a, decay_a,
                WqqB, bqh, KVT, ldkv, ti, preb);
    else if (t > 0)
      outk_body(t-1, bid-64, tid, smem, smem+512, actT, ao, bo_s,
                li_o, ri_o, decay_o, WoutB, bout, out);
  } else {
    PIGGY_CALL;
  }
}

__global__ __launch_bounds__(512) void stageB(
    const short* __restrict__ preb, const short* __restrict__ WsynP,
    const float* __restrict__ bsynF, float* __restrict__ u, PIGGY_ARGS)
{
  __shared__ __attribute__((aligned(16))) char pool[49152];
  const int bid = blockIdx.x, tid = threadIdx.x;
  if (bid < 128) synglu_body(bid, tid, pool, preb, WsynP, bsynF, u);
  else PIGGY_CALL;
}

__global__ __launch_bounds__(512) void stageC(
    const float* __restrict__ u, const float* __restrict__ gsyn,
    const float* __restrict__ bln, float* __restrict__ hist,
    const float* __restrict__ W1, const float* __restrict__ b1,
    const float* __restrict__ W2, const float* __restrict__ b2,
    float* __restrict__ actT, short* __restrict__ preb, int t, PIGGY_ARGS)
{
  __shared__ __attribute__((aligned(16))) char pool[49152];
  const int bid = blockIdx.x, tid = threadIdx.x;
  if (bid < 128) nlmln_body(bid, tid, pool, u, gsyn, bln, hist,
                            W1, b1, W2, b2, actT, preb, t);
  else PIGGY_CALL;
}

// Final outk for t = T-1.
__global__ __launch_bounds__(512) void outk_fin(
    const float* __restrict__ actT,
    float* __restrict__ ao, float* __restrict__ bo_s,
    const int* __restrict__ li_o, const int* __restrict__ ri_o,
    const float* __restrict__ decay_o,
    const short* __restrict__ WoutB, const float* __restrict__ bout,
    float* __restrict__ out)
{
  __shared__ __attribute__((aligned(16))) float smem[544];
  outk_body(T_-1, blockIdx.x, threadIdx.x, smem, smem+512, actT, ao, bo_s,
            li_o, ri_o, decay_o, WoutB, bout, out);
}

// ---------------------------------------------------------------------------
// Standalone transpose of x over [t0, t0+tc): f32 [B][T][DF][S] -> bf16 rows
// ((t*B+b)*S + s) x [DF]  (global-t row indexing).
// ---------------------------------------------------------------------------
__global__ __launch_bounds__(256) void xpose_x(const float* __restrict__ x,
                                               short* __restrict__ xT, int t0, int tc)
{
  __shared__ float tile[32][33];
  int df0 = blockIdx.x*32, s0 = blockIdx.y*32;
  int z = blockIdx.z;
  int b = z / tc, ti = z % tc;
  int tx = threadIdx.x & 31, ty = threadIdx.x >> 5;
  const float* src = x + (size_t)(b*T_ + t0 + ti) * DF_ * S_;
  #pragma unroll
  for (int i = 0; i < 4; ++i) {
    int df = df0 + ty + i*8;
    int s  = s0 + tx;
    tile[ty+i*8][tx] = (s < S_) ? src[(size_t)df*S_ + s] : 0.f;
  }
  __syncthreads();
  short* dst = xT + (size_t)((t0 + ti)*B_ + b) * S_ * DIN_;
  #pragma unroll
  for (int i = 0; i < 4; ++i) {
    int s  = s0 + ty + i*8;
    int df = df0 + tx;
    if (s < S_) dst[(size_t)s*DF_ + df] = f2b(tile[tx][ty+i*8]);
  }
}

// Standalone per-row LN stats (chunk-0 pipeline / fallback).
__global__ __launch_bounds__(256) void ln_stats(const short* __restrict__ in,
    float* __restrict__ mu, float* __restrict__ iv, int nrows)
{
  int w = threadIdx.x >> 6, l = threadIdx.x & 63;
  int r = blockIdx.x*4 + w;
  if (r >= nrows) return;
  bf16x8 v8 = *(const bf16x8*)&in[(size_t)r*512 + l*8];
  float s = 0.f, s2 = 0.f;
  #pragma unroll
  for (int j = 0; j < 8; ++j) { float v = b2f(v8[j]); s += v; s2 += v*v; }
  #pragma unroll
  for (int m = 1; m < 64; m <<= 1) { s += __shfl_xor(s, m, 64); s2 += __shfl_xor(s2, m, 64); }
  if (l == 0) {
    float mean = s * (1.f/512.f);
    float var  = s2 * (1.f/512.f) - mean*mean;
    mu[r] = mean;
    iv[r] = rsqrtf(var + 1e-5f);
  }
}

// Row permutation of WsynF so GLU pairs land in the same MFMA fragment.
__global__ __launch_bounds__(256) void permrows(const short* __restrict__ in,
                                                short* __restrict__ out)
{
  int r = blockIdx.x;
  int k = r >> 4, i = r & 15;
  int src = (i < 8) ? (k*8 + i) : (1024 + k*8 + (i - 8));
  const bf16x8* s = (const bf16x8*)(in + (size_t)src*1536);
  bf16x8* d = (bf16x8*)(out + (size_t)r*1536);
  int j = threadIdx.x;
  if (j < 192) d[j] = s[j];
}

// ---------------------------------------------------------------------------
// prep_all: all weight transposes, casts, bias folds and state init in ONE
// launch (segments dispatched on blockIdx.x; all segments independent).
// ---------------------------------------------------------------------------
__global__ __launch_bounds__(256) void prep_all(
    const float* __restrict__ Wkv, const float* __restrict__ Wk,
    const float* __restrict__ Wv,  const float* __restrict__ Wsyn,
    const float* __restrict__ Wq,  const float* __restrict__ Wqp,
    const float* __restrict__ Wo,  const float* __restrict__ Wout,
    const float* __restrict__ g_kv, const float* __restrict__ b_kv,
    const float* __restrict__ bk, const float* __restrict__ bv,
    const float* __restrict__ bqp, const float* __restrict__ bq,
    const float* __restrict__ bo_p, const float* __restrict__ bsyn,
    short* __restrict__ WkvT, short* __restrict__ WkkvT,
    short* __restrict__ WsynF, short* __restrict__ WsynTt,
    short* __restrict__ WqT, short* __restrict__ WqpB,
    short* __restrict__ WoB, short* __restrict__ WoutB,
    float* __restrict__ bqh, float* __restrict__ bsynF,
    float* __restrict__ gw, float* __restrict__ bw,
    float* __restrict__ aa, float* __restrict__ ba,
    float* __restrict__ ao, float* __restrict__ bo_s,
    float* __restrict__ actT, float* __restrict__ hist,
    short* __restrict__ preb,
    const float* __restrict__ init_act, const float* __restrict__ init_hist,
    const int* __restrict__ li_o, const int* __restrict__ ri_o)
{
  __shared__ float tile[32][33];
  const int blk = blockIdx.x, tid = threadIdx.x;
  auto wtr = [&](const float* in, short* out, int bx, int by,
                 int C, int ldo, int coff, const float* scale){
    int c0 = bx*32, r0 = by*32;
    int tx = tid & 31, ty = tid >> 5;
    #pragma unroll
    for (int i = 0; i < 4; ++i) {
      int r = r0+ty+i*8;
      float sc = scale ? scale[r] : 1.f;
      tile[ty+i*8][tx] = in[(size_t)r*C + c0+tx] * sc;
    }
    __syncthreads();
    #pragma unroll
    for (int i = 0; i < 4; ++i)
      out[(size_t)(c0+ty+i*8)*ldo + coff + r0+tx] = f2b(tile[tx][ty+i*8]);
  };
  auto cvt4 = [&](const float* in, short* out, int sb){
    int i = (sb*256 + tid)*4;
    #pragma unroll
    for (int j = 0; j < 4; ++j) out[i+j] = f2b(in[i+j]);
  };
  auto bfold = [&](const float* vec, const float* W, const float* base,
                   float* out, int n, int ldw){
    float a = base ? base[n] : 0.f;
    #pragma unroll 8
    for (int k = 0; k < 512; ++k) a += vec[k]*W[(size_t)k*ldw + n];
    out[n] = a;
  };

  if (blk < 256)       wtr(Wkv, WkvT, blk & 15, blk >> 4, 512, 512, 0, nullptr);
  else if (blk < 512)  { int s = blk-256;  wtr(Wk, WkkvT, s & 15, s >> 4, 512, 512, 0, g_kv); }
  else if (blk < 768)  { int s = blk-512;  wtr(Wv, WkkvT + (size_t)512*512, s & 15, s >> 4, 512, 512, 0, g_kv); }
  else if (blk < 2816) { int s = blk-768;  wtr(Wsyn + (size_t)512*2048, WsynF, s % 64, s / 64, 2048, 1536, 512, nullptr); }
  else if (blk < 3840) { int s = blk-2816; wtr(Wsyn, WsynTt, s % 64, s / 64, 2048, 512, 0, nullptr); }
  else if (blk < 4096) { int s = blk-3840; wtr(Wq, WqT, s & 15, s >> 4, 512, 512, 0, nullptr); }
  else if (blk < 4352) cvt4(Wqp,  WqpB,  blk-4096);
  else if (blk < 4608) cvt4(Wo,   WoB,   blk-4352);
  else if (blk < 4864) cvt4(Wout, WoutB, blk-4608);
  else if (blk < 4882) {
    int j = blk-4864;
    if (j < 2)        bfold(bqp,  Wq,   bq,   bqh,   j*256 + tid,      512);
    else if (j < 10)  bfold(bo_p, Wsyn, bsyn, bsynF, (j-2)*256 + tid,  2048);
    else if (j < 12)  bfold(g_kv, Wk,   nullptr, gw,       (j-10)*256 + tid, 512);
    else if (j < 14)  bfold(g_kv, Wv,   nullptr, gw + 512, (j-12)*256 + tid, 512);
    else if (j < 16)  bfold(b_kv, Wk,   bk,   bw,       (j-14)*256 + tid, 512);
    else              bfold(b_kv, Wv,   bv,   bw + 512, (j-16)*256 + tid, 512);
  } else {
    int i = (blk-4882)*256 + tid;
    if (i < 64*512) {
      aa[i] = 0.f; ba[i] = 0.f;
      int j = i & 511;
      ao[i] = init_act[li_o[j]] * init_act[ri_o[j]];
      bo_s[i] = 1.f;
    }
    if (i < 65536) {
      int n = i >> 6, b = i & 63;
      actT[i] = init_act[n];
      preb[(size_t)b*1536 + 512 + n] = f2b(init_act[n]);
    }
    if (i < DM_*MEM_*64) {
      int nm = i >> 6;
      hist[i] = init_hist[nm];
    }
  }
}

// ---------------------------------------------------------------------------
extern "C" void kernel_launch(void* const* d_in, const int* in_sizes, int n_in,
                              void* d_out, int out_size, void* d_ws, size_t ws_size,
                              hipStream_t stream)
{
  (void)in_sizes; (void)n_in; (void)out_size;
  const float* x       = (const float*)d_in[0];
  const float* Wqp     = (const float*)d_in[1];
  const float* bqp     = (const float*)d_in[2];
  const float* Wkv     = (const float*)d_in[3];
  const float* bkv     = (const float*)d_in[4];
  const float* g_kv    = (const float*)d_in[5];
  const float* b_kv    = (const float*)d_in[6];
  const float* Wq      = (const float*)d_in[7];
  const float* bq      = (const float*)d_in[8];
  const float* Wk      = (const float*)d_in[9];
  const float* bk      = (const float*)d_in[10];
  const float* Wv      = (const float*)d_in[11];
  const float* bv      = (const float*)d_in[12];
  const float* Wo      = (const float*)d_in[13];
  const float* bo_p    = (const float*)d_in[14];
  const float* Wsyn    = (const float*)d_in[15];
  const float* bsyn    = (const float*)d_in[16];
  const float* g_syn   = (const float*)d_in[17];
  const float* b_syn   = (const float*)d_in[18];
  const float* W1      = (const float*)d_in[19];
  const float* b1      = (const float*)d_in[20];
  const float* W2      = (const float*)d_in[21];
  const float* b2      = (const float*)d_in[22];
  const float* init_act  = (const float*)d_in[23];
  const float* init_hist = (const float*)d_in[24];
  const float* decay_a = (const float*)d_in[25];
  const float* decay_o = (const float*)d_in[26];
  const float* Wout    = (const float*)d_in[27];
  const float* bout    = (const float*)d_in[28];
  const int* li_a = (const int*)d_in[29];
  const int* ri_a = (const int*)d_in[30];
  const int* li_o = (const int*)d_in[31];
  const int* ri_o = (const int*)d_in[32];

  char* ws = (char*)d_ws;
  size_t off = 0;
  auto alloc = [&](size_t bytes) { char* p = ws + off; off += (bytes + 255) & ~(size_t)255; return p; };
  short* WkvT   = (short*)alloc(512*512*2);
  short* WkkvT  = (short*)alloc(1024*512*2);
  short* WsynF  = (short*)alloc(2048*1536*2);
  short* WsynP  = (short*)alloc(2048*1536*2);
  short* WsynTt = (short*)alloc(2048*512*2);
  short* WqpB   = (short*)alloc(512*512*2);
  short* WqT    = (short*)alloc(512*512*2);
  short* WoB    = (short*)alloc(512*512*2);
  short* WqqB   = (short*)alloc(512*512*2);
  short* WoutB  = (short*)alloc(512*512*2);
  float* bqh    = (float*)alloc(512*4);
  float* bsynF  = (float*)alloc(2048*4);
  float* gw     = (float*)alloc(1024*4);
  float* bw     = (float*)alloc(1024*4);
  short* preb   = (short*)alloc(64*1536*2);
  float* u      = (float*)alloc(64*1024*4);
  float* aa     = (float*)alloc(64*512*4);
  float* ba     = (float*)alloc(64*512*4);
  float* ao     = (float*)alloc(64*512*4);
  float* bo_s   = (float*)alloc(64*512*4);
  float* actT   = (float*)alloc(1024*64*4);
  float* hist   = (float*)alloc((size_t)1024*25*64*4);
  size_t fixed_end = off;

  const size_t szXT  = (size_t)T_*MR_*512*2;     // 205.5 MB (all 16 ticks)
  const size_t szKVP = (size_t)MCC_*512*2;       //  25.7 MB per chunk
  const size_t szKVT = (size_t)MCC_*1024*2;      //  51.4 MB per chunk
  const size_t szST  = (size_t)MCC_*4;
  size_t need_full = fixed_end + szXT + 2*szKVP + 2*szKVT + 4*szST + 4096;
  bool pig_en = (ws_size >= need_full);

  short* xT = (short*)alloc(szXT);
  short* kvpB[2]; short* KVTB[2]; float* muB[2]; float* ivB[2];
  kvpB[0] = (short*)alloc(szKVP);
  KVTB[0] = (short*)alloc(szKVT);
  muB[0]  = (float*)alloc(szST);
  ivB[0]  = (float*)alloc(szST);
  if (pig_en) {
    kvpB[1] = (short*)alloc(szKVP);
    KVTB[1] = (short*)alloc(szKVT);
    muB[1]  = (float*)alloc(szST);
    ivB[1]  = (float*)alloc(szST);
  } else {
    kvpB[1] = kvpB[0]; KVTB[1] = KVTB[0]; muB[1] = muB[0]; ivB[1] = ivB[0];
  }

  const int BIG = 1 << 30;
  const float* FN = nullptr;

  prep_all<<<11282, 256, 0, stream>>>(Wkv, Wk, Wv, Wsyn, Wq, Wqp, Wo, Wout,
      g_kv, b_kv, bk, bv, bqp, bq, bo_p, bsyn,
      WkvT, WkkvT, WsynF, WsynTt, WqT, WqpB, WoB, WoutB,
      bqh, bsynF, gw, bw, aa, ba, ao, bo_s, actT, hist, preb,
      init_act, init_hist, li_o, ri_o);
  gemm_prep2<<<80, 256, 0, stream>>>(WqpB, WqT, WqqB, WsynTt, WoB, WsynF);
  permrows<<<2048, 256, 0, stream>>>(WsynF, WsynP);

  // upfront transpose: chunk 0 only when piggybacking, all 16 ticks otherwise
  if (pig_en)
    xpose_x<<<dim3(16,7,B_*TC_), 256, 0, stream>>>(x, xT, 0, TC_);
  else
    xpose_x<<<dim3(16,7,B_*T_), 256, 0, stream>>>(x, xT, 0, T_);

  auto run_pipe = [&](int c, short* kvpP, float* muP, float* ivP, short* KVTP){
    const short* xTc = xT + (size_t)c*TC_*MR_*512;
    gemm_k<0,0><<<dim3(196,4), 256, 0, stream>>>(xTc, WkvT, kvpP, bkv, bkv, BIG,
                                                 FN, FN, FN, FN, MCC_, 512, 512, 512, 512);
    ln_stats<<<MCC_/4, 256, 0, stream>>>(kvpP, muP, ivP, MCC_);
    gemm_k<0,2><<<dim3(8,196), 256, 0, stream>>>(WkkvT, kvpP, KVTP, nullptr, nullptr, BIG,
                                                 muP, ivP, gw, bw, 1024, MCC_, 512, 512, MCC_);
  };

  // per-chunk piggy schedule over the 6 tail slots (TC_=2):
  // q0: op4 xpose (448); q1: op1 kv-GEMM (392 pairs); q2: op2 stats (392);
  // q3-5: op3 KVT-GEMM (262+262+260 pairs).
  auto pigcfg = [](int q, bool pig, int& op, int& pf, int& n){
    op = 0; pf = 0; n = 0;
    if (!pig) return;
    if (q == 0)      { op = 4; pf = 0;         n = 448; }
    else if (q == 1) { op = 1; pf = 0;         n = 392; }
    else if (q == 2) { op = 2; pf = 0;         n = 392; }
    else             { op = 3; pf = (q-3)*262; n = (q == 5) ? 260 : 262; }
  };

  run_pipe(0, kvpB[0], muB[0], ivB[0], KVTB[0]);

  for (int c = 0; c < NCH_; ++c) {
    int par = pig_en ? (c & 1) : 0;
    int nxt = pig_en ? (par ^ 1) : 0;
    if (!pig_en && c > 0) run_pipe(c, kvpB[0], muB[0], ivB[0], KVTB[0]);
    bool pig = pig_en && (c < NCH_-1);
    int t0n = (c < NCH_-1) ? (c+1)*TC_ : 0;
    for (int ti = 0; ti < TC_; ++ti) {
      int t = c*TC_ + ti;
      int op, pf, n;
      pigcfg(ti*3+0, pig, op, pf, n);
      stageA<<<128+n, 512, 0, stream>>>(actT, aa, ba, li_a, ri_a, decay_a,
          WqqB, bqh, KVTB[par], MCC_, ti, preb,
          ao, bo_s, li_o, ri_o, decay_o, WoutB, bout, (float*)d_out, t,
          op, pf, x, t0n, xT, WkvT, bkv, kvpB[nxt], muB[nxt], ivB[nxt],
          WkkvT, gw, bw, KVTB[nxt], MCC_);
      pigcfg(ti*3+1, pig, op, pf, n);
      stageB<<<128+n, 512, 0, stream>>>(preb, WsynP, bsynF, u,
          op, pf, x, t0n, xT, WkvT, bkv, kvpB[nxt], muB[nxt], ivB[nxt],
          WkkvT, gw, bw, KVTB[nxt], MCC_);
      pigcfg(ti*3+2, pig, op, pf, n);
      stageC<<<128+n, 512, 0, stream>>>(u, g_syn, b_syn, hist,
          W1, b1, W2, b2, actT, preb, t,
          op, pf, x, t0n, xT, WkvT, bkv, kvpB[nxt], muB[nxt], ivB[nxt],
          WkkvT, gw, bw, KVTB[nxt], MCC_);
    }
  }
  outk_fin<<<64, 512, 0, stream>>>(actT, ao, bo_s, li_o, ri_o, decay_o,
                                   WoutB, bout, (float*)d_out);
}